// Round 1
// 3649.648 us; speedup vs baseline: 2.7018x; 2.7018x over previous
//
#include <hip/hip_runtime.h>

#define D_S 128
#define D_F 1000
#define NH  4
#define NP  3
#define NB  4
#define SL  512
#define BL  (NB*SL)   // 2048 token rows

typedef unsigned short u16;
typedef unsigned int   u32;

using short8 = __attribute__((ext_vector_type(8))) short;  // 8 bf16 (4 VGPRs)
using f32x4  = __attribute__((ext_vector_type(4))) float;  // MFMA C/D

// ============================ gather ============================
__global__ __launch_bounds__(256) void gather_kernel(
    const int* __restrict__ tokens, const float* __restrict__ tok_mu,
    const float* __restrict__ tok_lv, const float* __restrict__ tok_ra,
    const float* __restrict__ tok_f, const float* __restrict__ pos_mu,
    float* __restrict__ mu, float* __restrict__ iv,
    float* __restrict__ alpha, float* __restrict__ feats)
{
    int row = blockIdx.x;            // b*SL + l
    int l = row & (SL - 1);
    int tok = tokens[row];
    for (int d = threadIdx.x; d < D_S; d += 256) {
        mu[row*D_S + d] = tok_mu[tok*D_S + d] + pos_mu[l*D_S + d];
        iv[row*D_S + d] = expf(-tok_lv[tok*D_S + d]);
    }
    if (threadIdx.x == 0)
        alpha[row] = 1.f / (1.f + expf(-tok_ra[tok]));
    for (int f = threadIdx.x; f < D_F; f += 256)
        feats[row*D_F + f] = tok_f[tok*D_F + f];
}

// ============================ fp32 -> bf16 hi/lo split ============================
// hi = truncate-to-bf16(x) (exact top 16 bits), lo = round-to-bf16(x - hi).
// x ~= hi + lo to ~24 bits. Zero-pads n>=N rows and k>=K cols into [Np][Kp].
__global__ __launch_bounds__(256) void split_hl(
    const float* __restrict__ src, u16* __restrict__ H, u16* __restrict__ L,
    int N, int K, int Np, int Kp)
{
    long total4 = (long)Np * Kp / 4;
    for (long i = (long)blockIdx.x * 256 + threadIdx.x; i < total4;
         i += (long)gridDim.x * 256) {
        long i4 = i * 4;
        int n = (int)(i4 / Kp);
        int k = (int)(i4 - (long)n * Kp);
        float v[4];
        if (n < N && k + 3 < K) {
            const float4 t = *(const float4*)(src + (long)n * K + k);
            v[0] = t.x; v[1] = t.y; v[2] = t.z; v[3] = t.w;
        } else {
            #pragma unroll
            for (int j = 0; j < 4; j++)
                v[j] = (n < N && k + j < K) ? src[(long)n * K + k + j] : 0.f;
        }
        u32 hh[4], ll[4];
        #pragma unroll
        for (int j = 0; j < 4; j++) {
            u32 b = __float_as_uint(v[j]);
            hh[j] = b >> 16;
            float r = v[j] - __uint_as_float(b & 0xffff0000u);
            u32 br = __float_as_uint(r);
            ll[j] = (br + 0x7fffu + ((br >> 16) & 1u)) >> 16;   // RNE-ish
        }
        uint2 hp, lp;
        hp.x = hh[0] | (hh[1] << 16); hp.y = hh[2] | (hh[3] << 16);
        lp.x = ll[0] | (ll[1] << 16); lp.y = ll[2] | (ll[3] << 16);
        *(uint2*)(H + i4) = hp;
        *(uint2*)(L + i4) = lp;
    }
}

// ============================ MFMA bf16x3 TN GEMM ============================
// C[M,N] = A[M,Kp] @ Bt[N,Kp]^T with A,B given as bf16 hi/lo pairs.
// A*B ~= Ah*Bh + Al*Bh + Ah*Bl  (error ~2^-16 relative, fp32-equivalent).
// 128x128 tile, BK=32, 4 waves (2x2), each wave 64x64 = 4x4 MFMA frags.
// EPI: 0=store, 1=+bias, 2=gelu(+bias), 3=C+=(+bias), 4=C+=tanh(+bias)
__device__ __forceinline__ void gl_lds16(const u16* g, u16* l) {
    __builtin_amdgcn_global_load_lds(
        (const __attribute__((address_space(1))) void*)g,
        (__attribute__((address_space(3))) void*)l, 16, 0, 0);
}

template<int EPI>
__global__ __launch_bounds__(256, 2) void gemm_bf3(
    const u16* __restrict__ Ah, const u16* __restrict__ Al,
    const u16* __restrict__ Bh, const u16* __restrict__ Bl,
    const float* __restrict__ bias, float* __restrict__ C,
    int M, int N, int Kp)
{
    // [128][32] bf16, linear: staging writes (lane-linear 16B) and b128 frag
    // reads are both bank-balanced (8 dwords/bank per wave access).
    __shared__ u16 sAh[128*32], sAl[128*32], sBh[128*32], sBl[128*32];
    const int tid = threadIdx.x;
    const int lane = tid & 63, wid = tid >> 6;
    const int wr = wid >> 1, wc = wid & 1;
    const int bm = blockIdx.y * 128, bn = blockIdx.x * 128;

    f32x4 acc[4][4];
    const f32x4 z = {0.f, 0.f, 0.f, 0.f};
    #pragma unroll
    for (int i = 0; i < 4; i++)
        #pragma unroll
        for (int j = 0; j < 4; j++) acc[i][j] = z;

    const int nkt = Kp >> 5;
    const int kg = (lane >> 4) << 3;          // k chunk: 0,8,16,24
    const int ar = (wr << 6) + (lane & 15);   // A frag base row in tile
    const int br = (wc << 6) + (lane & 15);   // B frag base row (=col) in tile

    for (int kt = 0; kt < nkt; ++kt) {
        const int kk = kt << 5;
        #pragma unroll
        for (int c = 0; c < 2; ++c) {          // 2 x 256 chunks of 16B per tile
            int i   = c * 256 + tid;
            int row = i >> 2;
            int kq  = (i & 3) << 3;
            long ga = (long)(bm + row) * Kp + kk + kq;
            long gb = (long)(bn + row) * Kp + kk + kq;
            int  le = i << 3;                  // element offset (i*16B)
            gl_lds16(Ah + ga, sAh + le);
            gl_lds16(Al + ga, sAl + le);
            gl_lds16(Bh + gb, sBh + le);
            gl_lds16(Bl + gb, sBl + le);
        }
        __syncthreads();                       // drains vmcnt before barrier

        short8 a_h[4], a_l[4], b_h[4], b_l[4];
        #pragma unroll
        for (int t = 0; t < 4; ++t) {
            a_h[t] = *(const short8*)&sAh[(ar + t*16)*32 + kg];
            a_l[t] = *(const short8*)&sAl[(ar + t*16)*32 + kg];
            b_h[t] = *(const short8*)&sBh[(br + t*16)*32 + kg];
            b_l[t] = *(const short8*)&sBl[(br + t*16)*32 + kg];
        }
        #pragma unroll
        for (int mi = 0; mi < 4; ++mi)
            #pragma unroll
            for (int ni = 0; ni < 4; ++ni) {
                f32x4 cacc = acc[mi][ni];
                cacc = __builtin_amdgcn_mfma_f32_16x16x32_bf16(a_h[mi], b_h[ni], cacc, 0, 0, 0);
                cacc = __builtin_amdgcn_mfma_f32_16x16x32_bf16(a_l[mi], b_h[ni], cacc, 0, 0, 0);
                cacc = __builtin_amdgcn_mfma_f32_16x16x32_bf16(a_h[mi], b_l[ni], cacc, 0, 0, 0);
                acc[mi][ni] = cacc;
            }
        __syncthreads();
    }

    // epilogue: C/D layout col=lane&15, row=(lane>>4)*4+reg [m89-verified]
    const int r0 = bm + (wr << 6) + ((lane >> 4) << 2);
    const int c0 = bn + (wc << 6) + (lane & 15);
    #pragma unroll
    for (int mi = 0; mi < 4; ++mi) {
        #pragma unroll
        for (int ni = 0; ni < 4; ++ni) {
            int cg = c0 + ni * 16;
            if (cg >= N) continue;
            float bv = (EPI == 0) ? 0.f : bias[cg];
            #pragma unroll
            for (int r = 0; r < 4; ++r) {
                int rg = r0 + mi * 16 + r;     // M always multiple of 128
                long idx = (long)rg * N + cg;
                float v = acc[mi][ni][r];
                if (EPI == 0)      C[idx] = v;
                else if (EPI == 1) C[idx] = v + bv;
                else if (EPI == 2) { float u = v + bv; C[idx] = 0.5f*u*(1.f + erff(u*0.70710678118654752f)); }
                else if (EPI == 3) C[idx] += v + bv;
                else if (EPI == 4) C[idx] += tanhf(v + bv);
            }
        }
    }
}

// ============================ generic TN GEMM (fp32 fallback) ============================
template<int EPI>
__global__ __launch_bounds__(256) void gemm_tn(
    const float* __restrict__ A, const float* __restrict__ Bt,
    const float* __restrict__ bias, float* __restrict__ C,
    int M, int N, int K)
{
    const int BM = 64, BN = 64, BK = 16;
    __shared__ float As[BK][BM + 4];
    __shared__ float Bs[BK][BN + 4];
    int tid = threadIdx.x;
    int tx = tid & 15, ty = tid >> 4;
    int bm = blockIdx.y * BM, bn = blockIdx.x * BN;
    int lr = tid >> 2;
    int lk = (tid & 3) * 4;
    float acc[4][4] = {};
    for (int kk = 0; kk < K; kk += BK) {
        int gr = bm + lr;
        int gn = bn + lr;
        #pragma unroll
        for (int i = 0; i < 4; i++) {
            int gk = kk + lk + i;
            As[lk + i][lr] = (gr < M && gk < K) ? A[(long)gr*K + gk] : 0.f;
            Bs[lk + i][lr] = (gn < N && gk < K) ? Bt[(long)gn*K + gk] : 0.f;
        }
        __syncthreads();
        #pragma unroll
        for (int k = 0; k < BK; k++) {
            float4 av = *(const float4*)&As[k][ty << 2];
            float4 bv = *(const float4*)&Bs[k][tx << 2];
            float a[4] = {av.x, av.y, av.z, av.w};
            float b[4] = {bv.x, bv.y, bv.z, bv.w};
            #pragma unroll
            for (int i = 0; i < 4; i++)
                #pragma unroll
                for (int j = 0; j < 4; j++)
                    acc[i][j] += a[i] * b[j];
        }
        __syncthreads();
    }
    #pragma unroll
    for (int i = 0; i < 4; i++) {
        int r = bm + (ty << 2) + i;
        if (r >= M) continue;
        #pragma unroll
        for (int j = 0; j < 4; j++) {
            int c = bn + (tx << 2) + j;
            if (c >= N) continue;
            float v = acc[i][j];
            long idx = (long)r*N + c;
            if (EPI == 0)      C[idx] = v;
            else if (EPI == 1) C[idx] = v + bias[c];
            else if (EPI == 2) { v += bias[c]; C[idx] = 0.5f*v*(1.f + erff(v*0.70710678118654752f)); }
            else if (EPI == 3) C[idx] += v + bias[c];
            else if (EPI == 4) C[idx] += tanhf(v + bias[c]);
        }
    }
}

// ============================ NN GEMM for mh ============================
__global__ __launch_bounds__(256) void gemm_mh(
    const float* __restrict__ Wfull, const float* __restrict__ feats,
    float* __restrict__ mh)
{
    const int BM = 64, BN = 64, BK = 16;
    const int M = NH*SL, N = D_F, K = SL;
    __shared__ float As[BK][BM + 4];
    __shared__ float Bs[BK][BN + 4];
    int b = blockIdx.z;
    const float* A  = Wfull + (long)b*M*K;
    const float* Bm = feats + (long)b*SL*D_F;
    int tid = threadIdx.x;
    int tx = tid & 15, ty = tid >> 4;
    int bm = blockIdx.y * BM, bn = blockIdx.x * BN;
    int kmax = (bm & (SL - 1)) + BM;
    int lrA = tid >> 2, lkA = (tid & 3) * 4;
    int lkB = tid >> 4, lnB = (tid & 15) * 4;
    float acc[4][4] = {};
    for (int kk = 0; kk < kmax; kk += BK) {
        #pragma unroll
        for (int i = 0; i < 4; i++)
            As[lkA + i][lrA] = A[(long)(bm + lrA)*K + kk + lkA + i];
        #pragma unroll
        for (int j = 0; j < 4; j++) {
            int gn = bn + lnB + j;
            Bs[lkB][lnB + j] = (gn < N) ? Bm[(long)(kk + lkB)*N + gn] : 0.f;
        }
        __syncthreads();
        #pragma unroll
        for (int k = 0; k < BK; k++) {
            float4 av = *(const float4*)&As[k][ty << 2];
            float4 bv = *(const float4*)&Bs[k][tx << 2];
            float a[4] = {av.x, av.y, av.z, av.w};
            float bb[4] = {bv.x, bv.y, bv.z, bv.w};
            #pragma unroll
            for (int i = 0; i < 4; i++)
                #pragma unroll
                for (int j = 0; j < 4; j++)
                    acc[i][j] += a[i] * bb[j];
        }
        __syncthreads();
    }
    int h = bm / SL;
    #pragma unroll
    for (int i = 0; i < 4; i++) {
        int r = bm + (ty << 2) + i;
        int l = r & (SL - 1);
        long orow = ((long)(b*SL + l)*NH + h) * D_F;
        #pragma unroll
        for (int j = 0; j < 4; j++) {
            int c = bn + (tx << 2) + j;
            if (c < N) mh[orow + c] = acc[i][j];
        }
    }
}

// ============================ attention ============================
__global__ __launch_bounds__(256) void attn_kernel(
    const float* __restrict__ q,
    const float* __restrict__ mu,
    const float* __restrict__ iv,
    const float* __restrict__ alpha,
    const float* __restrict__ log_tau,
    float* __restrict__ wout)
{
    int l = blockIdx.x, h = blockIdx.y, b = blockIdx.z;
    int tid = threadIdx.x, lane = tid & 63, wid = tid >> 6;
    __shared__ float qs[D_S];
    __shared__ float eff_s[SL];
    float scale = -0.5f / expf(log_tau[0]);
    if (tid < D_S)
        qs[tid] = q[(long)(b*SL + l)*(NH*D_S) + h*D_S + tid];
    for (int j = tid; j < SL; j += 256) eff_s[j] = 0.f;
    __syncthreads();
    for (int j = wid; j <= l; j += 4) {
        const float* mup = mu + (long)(b*SL + j)*D_S;
        const float* ivp = iv + (long)(b*SL + j)*D_S;
        float t0 = qs[lane]      - mup[lane];
        float t1 = qs[lane + 64] - mup[lane + 64];
        float s = ivp[lane]*t0*t0 + ivp[lane + 64]*t1*t1;
        #pragma unroll
        for (int o = 32; o > 0; o >>= 1) s += __shfl_xor(s, o);
        if (lane == 0) {
            float Kv = expf(scale * s);
            float e  = fminf(alpha[b*SL + j] * Kv, 1.f - 1e-6f);
            eff_s[j] = e;
        }
    }
    __syncthreads();
    if (wid == 0) {
        float carry = 0.f;
        long orow = (((long)b*NH + h)*SL + l)*SL;
        for (int c = 0; c < SL/64; c++) {
            int j = c*64 + lane;
            float e  = eff_s[j];
            float le = log1pf(-e);
            float sc = le;
            #pragma unroll
            for (int o = 1; o < 64; o <<= 1) {
                float v = __shfl_up(sc, o);
                if (lane >= o) sc += v;
            }
            float logT = carry + sc - le;
            wout[orow + j] = e * expf(logT);
            carry += __shfl(sc, 63);
        }
    }
}

// ============================ x = concat(feats, meaning) ============================
__global__ __launch_bounds__(256) void build_x(
    const float* __restrict__ feats, const float* __restrict__ meaning,
    float* __restrict__ x)
{
    long i = (long)blockIdx.x*256 + threadIdx.x;
    if (i < (long)BL*D_F) {
        int r = (int)(i / D_F), c = (int)(i % D_F);
        x[(long)r*2*D_F + c]       = feats[i];
        x[(long)r*2*D_F + D_F + c] = meaning[i];
    }
}

// ============================ alpha gate ============================
__global__ __launch_bounds__(256) void gate_kernel(
    const float* __restrict__ x, const float* __restrict__ Wg,
    const float* __restrict__ bg, float* __restrict__ alpha)
{
    int r = blockIdx.x;
    int tid = threadIdx.x, lane = tid & 63, wid = tid >> 6;
    float s = 0.f;
    for (int c = tid; c < 2*D_F; c += 256)
        s += x[(long)r*2*D_F + c] * Wg[c];
    #pragma unroll
    for (int o = 32; o > 0; o >>= 1) s += __shfl_xor(s, o);
    __shared__ float red[4];
    if (lane == 0) red[wid] = s;
    __syncthreads();
    if (tid == 0) {
        float t = red[0] + red[1] + red[2] + red[3] + bg[0];
        alpha[r] *= 1.f / (1.f + expf(-t));
    }
}

// ============================ layernorm ============================
__global__ __launch_bounds__(256) void ln_kernel(
    const float* __restrict__ x, const float* __restrict__ g,
    const float* __restrict__ bsh, float* __restrict__ o, int D)
{
    int r = blockIdx.x;
    const float* xr = x + (long)r*D;
    int tid = threadIdx.x, lane = tid & 63, wid = tid >> 6;
    float s = 0.f, s2 = 0.f;
    for (int c = tid; c < D; c += 256) { float v = xr[c]; s += v; s2 += v*v; }
    #pragma unroll
    for (int o = 32; o > 0; o >>= 1) { s += __shfl_xor(s, o); s2 += __shfl_xor(s2, o); }
    __shared__ float rs[4], rs2[4], stat[2];
    if (lane == 0) { rs[wid] = s; rs2[wid] = s2; }
    __syncthreads();
    if (tid == 0) {
        float a = rs[0] + rs[1] + rs[2] + rs[3];
        float bb = rs2[0] + rs2[1] + rs2[2] + rs2[3];
        float mean = a / D;
        float var = bb / D - mean*mean;
        if (var < 0.f) var = 0.f;
        stat[0] = mean;
        stat[1] = 1.f / sqrtf(var + 1e-5f);
    }
    __syncthreads();
    float mean = stat[0], inv = stat[1];
    for (int c = tid; c < D; c += 256)
        o[(long)r*D + c] = (xr[c] - mean)*inv*g[c] + bsh[c];
}

// ============================ launch ============================
extern "C" void kernel_launch(void* const* d_in, const int* in_sizes, int n_in,
                              void* d_out, int out_size, void* d_ws, size_t ws_size,
                              hipStream_t stream)
{
    const int*   tokens  = (const int*)  d_in[0];
    const float* tok_mu  = (const float*)d_in[1];
    const float* tok_lv  = (const float*)d_in[2];
    const float* tok_ra  = (const float*)d_in[3];
    const float* tok_f   = (const float*)d_in[4];
    const float* pos_mu  = (const float*)d_in[5];
    const float* log_tau = (const float*)d_in[6];
    const float* Wq      = (const float*)d_in[7];
    const float* bq      = (const float*)d_in[8];
    const float* Whead   = (const float*)d_in[9];
    const float* bhead   = (const float*)d_in[10];
    const float* Wmu     = (const float*)d_in[11];
    const float* bmu     = (const float*)d_in[12];
    const float* Wg      = (const float*)d_in[13];
    const float* bg      = (const float*)d_in[14];
    const float* ln_g    = (const float*)d_in[15];
    const float* ln_b    = (const float*)d_in[16];
    const float* W1      = (const float*)d_in[17];
    const float* b1      = (const float*)d_in[18];
    const float* W2      = (const float*)d_in[19];
    const float* b2      = (const float*)d_in[20];
    const float* lnf_g   = (const float*)d_in[21];
    const float* lnf_b   = (const float*)d_in[22];
    const float* Wlm     = (const float*)d_in[23];
    float* out = (float*)d_out;

    // ---- workspace carve ----
    float* ws = (float*)d_ws;
    size_t off = 0;
    auto alloc = [&](size_t n) { float* p = ws + off; off += n; return p; };
    float* mu      = alloc((size_t)BL*D_S);
    float* iv      = alloc((size_t)BL*D_S);
    float* alpha   = alloc((size_t)BL);
    float* feats   = alloc((size_t)BL*D_F);
    float* q       = alloc((size_t)BL*NH*D_S);
    float* w       = alloc((size_t)NB*NH*SL*SL);
    float* mh      = alloc((size_t)BL*NH*D_F);
    float* meaning = alloc((size_t)BL*D_F);
    float* x       = alloc((size_t)BL*2*D_F);
    float* hbuf = w;
    float* y    = w;
    float* t    = mh;

    // bf16 hi/lo region (after the fp32 region, 256B aligned)
    size_t offb = (off*sizeof(float) + 255) & ~(size_t)255;
    auto alloc16 = [&](size_t n) {
        u16* p = (u16*)((char*)d_ws + offb);
        offb = (offb + n*2 + 255) & ~(size_t)255;
        return p;
    };
    u16 *Ah     = alloc16((size_t)2048*4000), *Al     = alloc16((size_t)2048*4000);
    u16 *WqH    = alloc16((size_t)512*128),   *WqL    = alloc16((size_t)512*128);
    u16 *WheadH = alloc16((size_t)1024*4000), *WheadL = alloc16((size_t)1024*4000);
    u16 *WmuH   = alloc16((size_t)256*2016),  *WmuL   = alloc16((size_t)256*2016);
    u16 *W1H    = alloc16((size_t)2*4096*2016), *W1L  = alloc16((size_t)2*4096*2016);
    u16 *W2H    = alloc16((size_t)2*1024*4000), *W2L  = alloc16((size_t)2*1024*4000);
    u16 *WlmH   = alloc16((size_t)32000*1024),  *WlmL = alloc16((size_t)32000*1024);
    const bool use_mfma = ws_size >= offb;   // ~370 MB needed; else fp32 fallback

    auto SPL = [&](const float* W_, u16* H_, u16* L_, int N_, int K_, int Np_, int Kp_) {
        long t4 = (long)Np_ * Kp_ / 4;
        int nb = (int)((t4 + 255) / 256);
        if (nb > 2048) nb = 2048;
        split_hl<<<nb, 256, 0, stream>>>(W_, H_, L_, N_, K_, Np_, Kp_);
    };
    auto ASPL = [&](const float* A_, int K_, int Kp_) {
        long t4 = (long)2048 * Kp_ / 4;
        int nb = (int)((t4 + 255) / 256);
        if (nb > 2048) nb = 2048;
        split_hl<<<nb, 256, 0, stream>>>(A_, Ah, Al, 2048, K_, 2048, Kp_);
    };

    gather_kernel<<<BL, 256, 0, stream>>>(tokens, tok_mu, tok_lv, tok_ra, tok_f,
                                          pos_mu, mu, iv, alpha, feats);

    if (use_mfma) {
        // ---- one-time weight splits (memory-bound, ~100us total) ----
        SPL(Wq,    WqH,    WqL,    512,   128,  512,   128);
        SPL(Whead, WheadH, WheadL, 1000,  4000, 1024,  4000);
        SPL(Wmu,   WmuH,   WmuL,   256,   2000, 256,   2016);   // [2][128][2000] stacked
        for (int p = 0; p < 2; p++) {
            SPL(W1 + (size_t)p*4000*2000, W1H + (size_t)p*4096*2016,
                W1L + (size_t)p*4096*2016, 4000, 2000, 4096, 2016);
            SPL(W2 + (size_t)p*1000*4000, W2H + (size_t)p*1024*4000,
                W2L + (size_t)p*1024*4000, 1000, 4000, 1024, 4000);
        }
        SPL(Wlm, WlmH, WlmL, 32000, 1000, 32000, 1024);

        for (int p = 0; p < NP; p++) {
            // q = mu @ Wq.T + bq
            ASPL(mu, 128, 128);
            gemm_bf3<1><<<dim3(4, 16), 256, 0, stream>>>(Ah, Al, WqH, WqL, bq, q,
                                                         BL, NH*D_S, 128);
            attn_kernel<<<dim3(SL, NH, NB), 256, 0, stream>>>(q, mu, iv, alpha, log_tau, w);
            gemm_mh<<<dim3(16, 32, NB), 256, 0, stream>>>(w, feats, mh);
            // meaning = mh @ Whead.T + bhead
            ASPL(mh, 4000, 4000);
            gemm_bf3<1><<<dim3(8, 16), 256, 0, stream>>>(Ah, Al, WheadH, WheadL, bhead,
                                                         meaning, BL, D_F, 4000);
            if (p < NP - 1) {
                build_x<<<(BL*D_F + 255)/256, 256, 0, stream>>>(feats, meaning, x);
                gate_kernel<<<BL, 256, 0, stream>>>(x, Wg + (size_t)p*2*D_F, bg + p, alpha);
                // mu += tanh(x @ Wmu[p].T + bmu[p])
                ASPL(x, 2000, 2016);
                gemm_bf3<4><<<dim3(1, 16), 256, 0, stream>>>(
                    Ah, Al, WmuH + (size_t)p*128*2016, WmuL + (size_t)p*128*2016,
                    bmu + (size_t)p*D_S, mu, BL, D_S, 2016);
                ln_kernel<<<BL, 256, 0, stream>>>(x, ln_g + (size_t)p*2*D_F,
                                                  ln_b + (size_t)p*2*D_F, hbuf, 2*D_F);
                // t = gelu(h @ W1[p].T + b1[p])
                ASPL(hbuf, 2000, 2016);
                gemm_bf3<2><<<dim3(32, 16), 256, 0, stream>>>(
                    Ah, Al, W1H + (size_t)p*4096*2016, W1L + (size_t)p*4096*2016,
                    b1 + (size_t)p*4*D_F, t, BL, 4*D_F, 2016);
                // feats += t @ W2[p].T + b2[p]
                ASPL(t, 4000, 4000);
                gemm_bf3<3><<<dim3(8, 16), 256, 0, stream>>>(
                    Ah, Al, W2H + (size_t)p*1024*4000, W2L + (size_t)p*1024*4000,
                    b2 + (size_t)p*D_F, feats, BL, D_F, 4000);
            }
        }
        ln_kernel<<<BL, 256, 0, stream>>>(meaning, lnf_g, lnf_b, y, D_F);
        ASPL(y, 1000, 1024);
        gemm_bf3<0><<<dim3(250, 16), 256, 0, stream>>>(Ah, Al, WlmH, WlmL, nullptr, out,
                                                       BL, 32000, 1024);
    } else {
        // ---- fp32 fallback (previous proven path) ----
        for (int p = 0; p < NP; p++) {
            gemm_tn<1><<<dim3(8, 32), 256, 0, stream>>>(mu, Wq, bq, q, BL, NH*D_S, D_S);
            attn_kernel<<<dim3(SL, NH, NB), 256, 0, stream>>>(q, mu, iv, alpha, log_tau, w);
            gemm_mh<<<dim3(16, 32, NB), 256, 0, stream>>>(w, feats, mh);
            gemm_tn<1><<<dim3(16, 32), 256, 0, stream>>>(mh, Whead, bhead, meaning, BL, D_F, NH*D_F);
            if (p < NP - 1) {
                build_x<<<(BL*D_F + 255)/256, 256, 0, stream>>>(feats, meaning, x);
                gate_kernel<<<BL, 256, 0, stream>>>(x, Wg + (size_t)p*2*D_F, bg + p, alpha);
                gemm_tn<4><<<dim3(2, 32), 256, 0, stream>>>(x, Wmu + (size_t)p*D_S*2*D_F,
                                                            bmu + (size_t)p*D_S, mu, BL, D_S, 2*D_F);
                ln_kernel<<<BL, 256, 0, stream>>>(x, ln_g + (size_t)p*2*D_F, ln_b + (size_t)p*2*D_F,
                                                  hbuf, 2*D_F);
                gemm_tn<2><<<dim3(63, 32), 256, 0, stream>>>(hbuf, W1 + (size_t)p*4*D_F*2*D_F,
                                                             b1 + (size_t)p*4*D_F, t, BL, 4*D_F, 2*D_F);
                gemm_tn<3><<<dim3(16, 32), 256, 0, stream>>>(t, W2 + (size_t)p*D_F*4*D_F,
                                                             b2 + (size_t)p*D_F, feats, BL, D_F, 4*D_F);
            }
        }
        ln_kernel<<<BL, 256, 0, stream>>>(meaning, lnf_g, lnf_b, y, D_F);
        gemm_tn<0><<<dim3(500, 32), 256, 0, stream>>>(y, Wlm, nullptr, out, BL, 32000, D_F);
    }
}

// Round 2
// 2915.585 us; speedup vs baseline: 3.3820x; 1.2518x over previous
//
#include <hip/hip_runtime.h>

#define D_S 128
#define D_F 1000
#define NH  4
#define NP  3
#define NB  4
#define SL  512
#define BL  (NB*SL)   // 2048 token rows

typedef unsigned short u16;
typedef unsigned int   u32;

using short8 = __attribute__((ext_vector_type(8))) short;  // 8 bf16 (4 VGPRs)
using f32x4  = __attribute__((ext_vector_type(4))) float;  // MFMA C/D

// ============================ gather ============================
__global__ __launch_bounds__(256) void gather_kernel(
    const int* __restrict__ tokens, const float* __restrict__ tok_mu,
    const float* __restrict__ tok_lv, const float* __restrict__ tok_ra,
    const float* __restrict__ tok_f, const float* __restrict__ pos_mu,
    float* __restrict__ mu, float* __restrict__ iv,
    float* __restrict__ alpha, float* __restrict__ feats)
{
    int row = blockIdx.x;            // b*SL + l
    int l = row & (SL - 1);
    int tok = tokens[row];
    for (int d = threadIdx.x; d < D_S; d += 256) {
        mu[row*D_S + d] = tok_mu[tok*D_S + d] + pos_mu[l*D_S + d];
        iv[row*D_S + d] = expf(-tok_lv[tok*D_S + d]);
    }
    if (threadIdx.x == 0)
        alpha[row] = 1.f / (1.f + expf(-tok_ra[tok]));
    for (int f = threadIdx.x; f < D_F; f += 256)
        feats[row*D_F + f] = tok_f[tok*D_F + f];
}

// ============================ fp32 -> bf16 hi/lo split helpers ============================
__device__ __forceinline__ void split1(float v, u16* __restrict__ H,
                                       u16* __restrict__ L, long idx)
{
    u32 b = __float_as_uint(v);
    H[idx] = (u16)(b >> 16);
    float r = v - __uint_as_float(b & 0xffff0000u);
    u32 br = __float_as_uint(r);
    L[idx] = (u16)((br + 0x7fffu + ((br >> 16) & 1u)) >> 16);
}

__global__ __launch_bounds__(256) void split_hl(
    const float* __restrict__ src, u16* __restrict__ H, u16* __restrict__ L,
    int N, int K, int Np, int Kp)
{
    long total4 = (long)Np * Kp / 4;
    for (long i = (long)blockIdx.x * 256 + threadIdx.x; i < total4;
         i += (long)gridDim.x * 256) {
        long i4 = i * 4;
        int n = (int)(i4 / Kp);
        int k = (int)(i4 - (long)n * Kp);
        float v[4];
        if (n < N && k + 3 < K) {
            const float4 t = *(const float4*)(src + (long)n * K + k);
            v[0] = t.x; v[1] = t.y; v[2] = t.z; v[3] = t.w;
        } else {
            #pragma unroll
            for (int j = 0; j < 4; j++)
                v[j] = (n < N && k + j < K) ? src[(long)n * K + k + j] : 0.f;
        }
        u32 hh[4], ll[4];
        #pragma unroll
        for (int j = 0; j < 4; j++) {
            u32 b = __float_as_uint(v[j]);
            hh[j] = b >> 16;
            float r = v[j] - __uint_as_float(b & 0xffff0000u);
            u32 br = __float_as_uint(r);
            ll[j] = (br + 0x7fffu + ((br >> 16) & 1u)) >> 16;
        }
        uint2 hp, lp;
        hp.x = hh[0] | (hh[1] << 16); hp.y = hh[2] | (hh[3] << 16);
        lp.x = ll[0] | (ll[1] << 16); lp.y = ll[2] | (ll[3] << 16);
        *(uint2*)(H + i4) = hp;
        *(uint2*)(L + i4) = lp;
    }
}

// ============================ MFMA bf16x3 TN GEMM ============================
__device__ __forceinline__ void gl_lds16(const u16* g, u16* l) {
    __builtin_amdgcn_global_load_lds(
        (const __attribute__((address_space(1))) void*)g,
        (__attribute__((address_space(3))) void*)l, 16, 0, 0);
}

// C[M,N] = A[M,Kp] @ Bt[N,Kp]^T, bf16 hi/lo pairs, 3-MFMA fp32-equivalent.
// 128x128 tile, BK=32, 4 waves (2x2). M-inner work order + XCD swizzle for
// B-panel L2 reuse (requires nwg % 8 == 0; all call sites satisfy this).
template<int EPI>
__global__ __launch_bounds__(256, 2) void gemm_bf3(
    const u16* __restrict__ Ah, const u16* __restrict__ Al,
    const u16* __restrict__ Bh, const u16* __restrict__ Bl,
    const float* __restrict__ bias, float* __restrict__ C,
    int M, int N, int Kp)
{
    __shared__ u16 sAh[128*32], sAl[128*32], sBh[128*32], sBl[128*32];
    const int tid = threadIdx.x;
    const int lane = tid & 63, wid = tid >> 6;
    const int wr = wid >> 1, wc = wid & 1;

    // XCD-aware bijective swizzle + M-inner mapping
    const int nmt = gridDim.y;                      // M tiles (16)
    const int nwg = gridDim.x * nmt;
    const int bid = blockIdx.y * gridDim.x + blockIdx.x;
    const int work = (bid & 7) * (nwg >> 3) + (bid >> 3);
    const int bm = (work % nmt) * 128;
    const int bn = (work / nmt) * 128;

    f32x4 acc[4][4];
    const f32x4 z = {0.f, 0.f, 0.f, 0.f};
    #pragma unroll
    for (int i = 0; i < 4; i++)
        #pragma unroll
        for (int j = 0; j < 4; j++) acc[i][j] = z;

    const int nkt = Kp >> 5;
    const int kg = (lane >> 4) << 3;
    const int ar = (wr << 6) + (lane & 15);
    const int br = (wc << 6) + (lane & 15);

    for (int kt = 0; kt < nkt; ++kt) {
        const int kk = kt << 5;
        #pragma unroll
        for (int c = 0; c < 2; ++c) {
            int i   = c * 256 + tid;
            int row = i >> 2;
            int kq  = (i & 3) << 3;
            long ga = (long)(bm + row) * Kp + kk + kq;
            long gb = (long)(bn + row) * Kp + kk + kq;
            int  le = i << 3;
            gl_lds16(Ah + ga, sAh + le);
            gl_lds16(Al + ga, sAl + le);
            gl_lds16(Bh + gb, sBh + le);
            gl_lds16(Bl + gb, sBl + le);
        }
        __syncthreads();

        short8 a_h[4], a_l[4], b_h[4], b_l[4];
        #pragma unroll
        for (int t = 0; t < 4; ++t) {
            a_h[t] = *(const short8*)&sAh[(ar + t*16)*32 + kg];
            a_l[t] = *(const short8*)&sAl[(ar + t*16)*32 + kg];
            b_h[t] = *(const short8*)&sBh[(br + t*16)*32 + kg];
            b_l[t] = *(const short8*)&sBl[(br + t*16)*32 + kg];
        }
        #pragma unroll
        for (int mi = 0; mi < 4; ++mi)
            #pragma unroll
            for (int ni = 0; ni < 4; ++ni) {
                f32x4 cacc = acc[mi][ni];
                cacc = __builtin_amdgcn_mfma_f32_16x16x32_bf16(a_h[mi], b_h[ni], cacc, 0, 0, 0);
                cacc = __builtin_amdgcn_mfma_f32_16x16x32_bf16(a_l[mi], b_h[ni], cacc, 0, 0, 0);
                cacc = __builtin_amdgcn_mfma_f32_16x16x32_bf16(a_h[mi], b_l[ni], cacc, 0, 0, 0);
                acc[mi][ni] = cacc;
            }
        __syncthreads();
    }

    const int r0 = bm + (wr << 6) + ((lane >> 4) << 2);
    const int c0 = bn + (wc << 6) + (lane & 15);
    #pragma unroll
    for (int mi = 0; mi < 4; ++mi) {
        #pragma unroll
        for (int ni = 0; ni < 4; ++ni) {
            int cg = c0 + ni * 16;
            if (cg >= N) continue;
            float bv = (EPI == 0) ? 0.f : bias[cg];
            #pragma unroll
            for (int r = 0; r < 4; ++r) {
                int rg = r0 + mi * 16 + r;
                long idx = (long)rg * N + cg;
                float v = acc[mi][ni][r];
                if (EPI == 0)      C[idx] = v;
                else if (EPI == 1) C[idx] = v + bv;
                else if (EPI == 2) { float u = v + bv; C[idx] = 0.5f*u*(1.f + erff(u*0.70710678118654752f)); }
                else if (EPI == 3) C[idx] += v + bv;
                else if (EPI == 4) C[idx] += tanhf(v + bv);
            }
        }
    }
}

// ============================ mahalanobis as MFMA GEMM ============================
// S[bh*512+l][j] = Aext[bh*512+l] . Bext[b*512+j], K=288.
// grid (4,4,16); tiles with bni>bmi (fully j>l) skipped.
__global__ __launch_bounds__(256, 2) void gemm_mahal(
    const u16* __restrict__ Ah, const u16* __restrict__ Al,
    const u16* __restrict__ Bh, const u16* __restrict__ Bl,
    float* __restrict__ S)
{
    const int KP = 288;
    __shared__ u16 sAh[128*32], sAl[128*32], sBh[128*32], sBl[128*32];
    const int bmi = blockIdx.y, bni = blockIdx.x;
    if (bni > bmi) return;
    const int tid = threadIdx.x;
    const int lane = tid & 63, wid = tid >> 6;
    const int wr = wid >> 1, wc = wid & 1;
    const int bh = blockIdx.z;
    const long arow0 = (long)bh * 512 + bmi * 128;
    const long brow0 = (long)(bh >> 2) * 512 + bni * 128;

    f32x4 acc[4][4];
    const f32x4 z = {0.f, 0.f, 0.f, 0.f};
    #pragma unroll
    for (int i = 0; i < 4; i++)
        #pragma unroll
        for (int j = 0; j < 4; j++) acc[i][j] = z;

    const int kg = (lane >> 4) << 3;
    const int ar = (wr << 6) + (lane & 15);
    const int br = (wc << 6) + (lane & 15);

    for (int kt = 0; kt < 9; ++kt) {
        const int kk = kt << 5;
        #pragma unroll
        for (int c = 0; c < 2; ++c) {
            int i   = c * 256 + tid;
            int row = i >> 2;
            int kq  = (i & 3) << 3;
            long ga = (arow0 + row) * KP + kk + kq;
            long gb = (brow0 + row) * KP + kk + kq;
            int  le = i << 3;
            gl_lds16(Ah + ga, sAh + le);
            gl_lds16(Al + ga, sAl + le);
            gl_lds16(Bh + gb, sBh + le);
            gl_lds16(Bl + gb, sBl + le);
        }
        __syncthreads();
        short8 a_h[4], a_l[4], b_h[4], b_l[4];
        #pragma unroll
        for (int t = 0; t < 4; ++t) {
            a_h[t] = *(const short8*)&sAh[(ar + t*16)*32 + kg];
            a_l[t] = *(const short8*)&sAl[(ar + t*16)*32 + kg];
            b_h[t] = *(const short8*)&sBh[(br + t*16)*32 + kg];
            b_l[t] = *(const short8*)&sBl[(br + t*16)*32 + kg];
        }
        #pragma unroll
        for (int mi = 0; mi < 4; ++mi)
            #pragma unroll
            for (int ni = 0; ni < 4; ++ni) {
                f32x4 cacc = acc[mi][ni];
                cacc = __builtin_amdgcn_mfma_f32_16x16x32_bf16(a_h[mi], b_h[ni], cacc, 0, 0, 0);
                cacc = __builtin_amdgcn_mfma_f32_16x16x32_bf16(a_l[mi], b_h[ni], cacc, 0, 0, 0);
                cacc = __builtin_amdgcn_mfma_f32_16x16x32_bf16(a_h[mi], b_l[ni], cacc, 0, 0, 0);
                acc[mi][ni] = cacc;
            }
        __syncthreads();
    }

    const int r0 = bmi * 128 + (wr << 6) + ((lane >> 4) << 2);
    const int c0 = bni * 128 + (wc << 6) + (lane & 15);
    #pragma unroll
    for (int mi = 0; mi < 4; ++mi)
        #pragma unroll
        for (int ni = 0; ni < 4; ++ni) {
            int cg = c0 + ni * 16;
            #pragma unroll
            for (int r = 0; r < 4; ++r) {
                int rg = r0 + mi * 16 + r;
                S[((long)bh * 512 + rg) * 512 + cg] = acc[mi][ni][r];
            }
        }
}

// ============================ build Aext / Bext ============================
// Aext[bh*512+l] = [q^2 (128), q (128), 1, 0...]   (K=288)
__global__ __launch_bounds__(256) void build_a_ext(
    const float* __restrict__ q, u16* __restrict__ H, u16* __restrict__ L)
{
    int row = blockIdx.x;            // bh*512 + l
    int bh = row >> 9, l = row & 511;
    int b = bh >> 2, h = bh & 3;
    const float* qp = q + (long)(b*SL + l)*(NH*D_S) + h*D_S;
    long base = (long)row * 288;
    for (int t = threadIdx.x; t < 288; t += 256) {
        float v;
        if (t < 128)      { float qq = qp[t]; v = qq*qq; }
        else if (t < 256)   v = qp[t-128];
        else if (t == 256)  v = 1.f;
        else                v = 0.f;
        split1(v, H, L, base + t);
    }
}

// Bext[b*512+j] = [iv (128), -2*mu*iv (128), sum(mu^2*iv), 0...]
__global__ __launch_bounds__(256) void build_b_ext(
    const float* __restrict__ mu, const float* __restrict__ iv,
    u16* __restrict__ H, u16* __restrict__ L)
{
    int row = blockIdx.x;            // b*SL + j
    int tid = threadIdx.x, lane = tid & 63;
    const float* mup = mu + (long)row*D_S;
    const float* ivp = iv + (long)row*D_S;
    __shared__ float red[2];
    float part = 0.f;
    if (tid < 128) { float m = mup[tid]; part = m*m*ivp[tid]; }
    #pragma unroll
    for (int o = 32; o > 0; o >>= 1) part += __shfl_xor(part, o);
    if (tid < 128 && lane == 0) red[tid >> 6] = part;
    __syncthreads();
    float mu2 = red[0] + red[1];
    long base = (long)row * 288;
    for (int t = tid; t < 288; t += 256) {
        float v;
        if (t < 128)        v = ivp[t];
        else if (t < 256)   v = -2.f * mup[t-128] * ivp[t-128];
        else if (t == 256)  v = mu2;
        else                v = 0.f;
        split1(v, H, L, base + t);
    }
}

// ============================ compositing scan (in-place S -> w) ============================
// One wave per row (b,h,l); grid 2048 blocks x 4 waves.
__global__ __launch_bounds__(256) void scan_kernel(
    float* __restrict__ S, const float* __restrict__ alpha,
    const float* __restrict__ log_tau)
{
    int row = blockIdx.x * 4 + (threadIdx.x >> 6);   // bh*512 + l
    int lane = threadIdx.x & 63;
    int b = row >> 11, l = row & 511;
    float scale = -0.5f * expf(-log_tau[0]);
    long base = (long)row * 512;
    float carry = 0.f;
    for (int c = 0; c < 8; c++) {
        int j = c*64 + lane;
        float e = 0.f;
        if (j <= l) {
            float Kv = expf(scale * S[base + j]);
            e = fminf(alpha[b*SL + j] * Kv, 1.f - 1e-6f);
        }
        float le = log1pf(-e);
        float sc = le;
        #pragma unroll
        for (int o = 1; o < 64; o <<= 1) {
            float v = __shfl_up(sc, o);
            if (lane >= o) sc += v;
        }
        float logT = carry + sc - le;
        S[base + j] = e * expf(logT);
        carry += __shfl(sc, 63);
    }
}

// ============================ feats transpose + split ============================
// fT[b][f][j] (f padded to 1024) = feats[b*SL+j][f], hi/lo bf16.
__global__ __launch_bounds__(256) void tsplit_feats(
    const float* __restrict__ feats, u16* __restrict__ H, u16* __restrict__ L)
{
    __shared__ float tile[32][33];
    int b = blockIdx.z, f0 = blockIdx.x*32, j0 = blockIdx.y*32;
    int tx = threadIdx.x & 31, ty = threadIdx.x >> 5;   // 32 x 8
    #pragma unroll
    for (int i = 0; i < 4; i++) {
        int j = j0 + ty + 8*i, f = f0 + tx;
        tile[ty + 8*i][tx] = (f < D_F) ? feats[(long)(b*SL + j)*D_F + f] : 0.f;
    }
    __syncthreads();
    #pragma unroll
    for (int i = 0; i < 4; i++) {
        int f = f0 + ty + 8*i, j = j0 + tx;
        split1(tile[tx][ty + 8*i], H, L, ((long)(b*1024 + f))*512 + j);
    }
}

// ============================ mh = w @ feats via MFMA ============================
// A = w split [b*2048 + h*512 + l][512]; Bt = fT[b] [1024][512].
// grid (8,16,4); causal kmax; permuted store to mh[((b*SL+l)*NH+h)*D_F + f].
__global__ __launch_bounds__(256, 2) void gemm_mh_bf3(
    const u16* __restrict__ Ah, const u16* __restrict__ Al,
    const u16* __restrict__ Bh, const u16* __restrict__ Bl,
    float* __restrict__ mh)
{
    const int KP = 512;
    __shared__ u16 sAh[128*32], sAl[128*32], sBh[128*32], sBl[128*32];
    const int tid = threadIdx.x;
    const int lane = tid & 63, wid = tid >> 6;
    const int wr = wid >> 1, wc = wid & 1;
    const int b = blockIdx.z;
    const int bm = blockIdx.y * 128;       // within [0,2048): h*512+l
    const int bn = blockIdx.x * 128;       // f
    const long arow0 = (long)b*2048 + bm;
    const long brow0 = (long)b*1024 + bn;
    const int kmax = (bm & 511) + 128;
    const int nkt = kmax >> 5;

    f32x4 acc[4][4];
    const f32x4 z = {0.f, 0.f, 0.f, 0.f};
    #pragma unroll
    for (int i = 0; i < 4; i++)
        #pragma unroll
        for (int j = 0; j < 4; j++) acc[i][j] = z;

    const int kg = (lane >> 4) << 3;
    const int ar = (wr << 6) + (lane & 15);
    const int br = (wc << 6) + (lane & 15);

    for (int kt = 0; kt < nkt; ++kt) {
        const int kk = kt << 5;
        #pragma unroll
        for (int c = 0; c < 2; ++c) {
            int i   = c * 256 + tid;
            int row = i >> 2;
            int kq  = (i & 3) << 3;
            long ga = (arow0 + row) * KP + kk + kq;
            long gb = (brow0 + row) * KP + kk + kq;
            int  le = i << 3;
            gl_lds16(Ah + ga, sAh + le);
            gl_lds16(Al + ga, sAl + le);
            gl_lds16(Bh + gb, sBh + le);
            gl_lds16(Bl + gb, sBl + le);
        }
        __syncthreads();
        short8 a_h[4], a_l[4], b_h[4], b_l[4];
        #pragma unroll
        for (int t = 0; t < 4; ++t) {
            a_h[t] = *(const short8*)&sAh[(ar + t*16)*32 + kg];
            a_l[t] = *(const short8*)&sAl[(ar + t*16)*32 + kg];
            b_h[t] = *(const short8*)&sBh[(br + t*16)*32 + kg];
            b_l[t] = *(const short8*)&sBl[(br + t*16)*32 + kg];
        }
        #pragma unroll
        for (int mi = 0; mi < 4; ++mi)
            #pragma unroll
            for (int ni = 0; ni < 4; ++ni) {
                f32x4 cacc = acc[mi][ni];
                cacc = __builtin_amdgcn_mfma_f32_16x16x32_bf16(a_h[mi], b_h[ni], cacc, 0, 0, 0);
                cacc = __builtin_amdgcn_mfma_f32_16x16x32_bf16(a_l[mi], b_h[ni], cacc, 0, 0, 0);
                cacc = __builtin_amdgcn_mfma_f32_16x16x32_bf16(a_h[mi], b_l[ni], cacc, 0, 0, 0);
                acc[mi][ni] = cacc;
            }
        __syncthreads();
    }

    const int r0 = bm + (wr << 6) + ((lane >> 4) << 2);
    const int c0 = bn + (wc << 6) + (lane & 15);
    #pragma unroll
    for (int mi = 0; mi < 4; ++mi) {
        #pragma unroll
        for (int ni = 0; ni < 4; ++ni) {
            int cg = c0 + ni * 16;
            if (cg >= D_F) continue;
            #pragma unroll
            for (int r = 0; r < 4; ++r) {
                int rg = r0 + mi * 16 + r;      // h*512+l
                int h = rg >> 9, l = rg & 511;
                mh[((long)(b*SL + l)*NH + h)*D_F + cg] = acc[mi][ni][r];
            }
        }
    }
}

// ============================ fp32 fallback kernels ============================
template<int EPI>
__global__ __launch_bounds__(256) void gemm_tn(
    const float* __restrict__ A, const float* __restrict__ Bt,
    const float* __restrict__ bias, float* __restrict__ C,
    int M, int N, int K)
{
    const int BM = 64, BN = 64, BK = 16;
    __shared__ float As[BK][BM + 4];
    __shared__ float Bs[BK][BN + 4];
    int tid = threadIdx.x;
    int tx = tid & 15, ty = tid >> 4;
    int bm = blockIdx.y * BM, bn = blockIdx.x * BN;
    int lr = tid >> 2;
    int lk = (tid & 3) * 4;
    float acc[4][4] = {};
    for (int kk = 0; kk < K; kk += BK) {
        int gr = bm + lr;
        int gn = bn + lr;
        #pragma unroll
        for (int i = 0; i < 4; i++) {
            int gk = kk + lk + i;
            As[lk + i][lr] = (gr < M && gk < K) ? A[(long)gr*K + gk] : 0.f;
            Bs[lk + i][lr] = (gn < N && gk < K) ? Bt[(long)gn*K + gk] : 0.f;
        }
        __syncthreads();
        #pragma unroll
        for (int k = 0; k < BK; k++) {
            float4 av = *(const float4*)&As[k][ty << 2];
            float4 bv = *(const float4*)&Bs[k][tx << 2];
            float a[4] = {av.x, av.y, av.z, av.w};
            float b[4] = {bv.x, bv.y, bv.z, bv.w};
            #pragma unroll
            for (int i = 0; i < 4; i++)
                #pragma unroll
                for (int j = 0; j < 4; j++)
                    acc[i][j] += a[i] * b[j];
        }
        __syncthreads();
    }
    #pragma unroll
    for (int i = 0; i < 4; i++) {
        int r = bm + (ty << 2) + i;
        if (r >= M) continue;
        #pragma unroll
        for (int j = 0; j < 4; j++) {
            int c = bn + (tx << 2) + j;
            if (c >= N) continue;
            float v = acc[i][j];
            long idx = (long)r*N + c;
            if (EPI == 0)      C[idx] = v;
            else if (EPI == 1) C[idx] = v + bias[c];
            else if (EPI == 2) { v += bias[c]; C[idx] = 0.5f*v*(1.f + erff(v*0.70710678118654752f)); }
            else if (EPI == 3) C[idx] += v + bias[c];
            else if (EPI == 4) C[idx] += tanhf(v + bias[c]);
        }
    }
}

__global__ __launch_bounds__(256) void gemm_mh(
    const float* __restrict__ Wfull, const float* __restrict__ feats,
    float* __restrict__ mh)
{
    const int BM = 64, BN = 64, BK = 16;
    const int M = NH*SL, N = D_F, K = SL;
    __shared__ float As[BK][BM + 4];
    __shared__ float Bs[BK][BN + 4];
    int b = blockIdx.z;
    const float* A  = Wfull + (long)b*M*K;
    const float* Bm = feats + (long)b*SL*D_F;
    int tid = threadIdx.x;
    int tx = tid & 15, ty = tid >> 4;
    int bm = blockIdx.y * BM, bn = blockIdx.x * BN;
    int kmax = (bm & (SL - 1)) + BM;
    int lrA = tid >> 2, lkA = (tid & 3) * 4;
    int lkB = tid >> 4, lnB = (tid & 15) * 4;
    float acc[4][4] = {};
    for (int kk = 0; kk < kmax; kk += BK) {
        #pragma unroll
        for (int i = 0; i < 4; i++)
            As[lkA + i][lrA] = A[(long)(bm + lrA)*K + kk + lkA + i];
        #pragma unroll
        for (int j = 0; j < 4; j++) {
            int gn = bn + lnB + j;
            Bs[lkB][lnB + j] = (gn < N) ? Bm[(long)(kk + lkB)*N + gn] : 0.f;
        }
        __syncthreads();
        #pragma unroll
        for (int k = 0; k < BK; k++) {
            float4 av = *(const float4*)&As[k][ty << 2];
            float4 bv = *(const float4*)&Bs[k][tx << 2];
            float a[4] = {av.x, av.y, av.z, av.w};
            float bb[4] = {bv.x, bv.y, bv.z, bv.w};
            #pragma unroll
            for (int i = 0; i < 4; i++)
                #pragma unroll
                for (int j = 0; j < 4; j++)
                    acc[i][j] += a[i] * bb[j];
        }
        __syncthreads();
    }
    int h = bm / SL;
    #pragma unroll
    for (int i = 0; i < 4; i++) {
        int r = bm + (ty << 2) + i;
        int l = r & (SL - 1);
        long orow = ((long)(b*SL + l)*NH + h) * D_F;
        #pragma unroll
        for (int j = 0; j < 4; j++) {
            int c = bn + (tx << 2) + j;
            if (c < N) mh[orow + c] = acc[i][j];
        }
    }
}

__global__ __launch_bounds__(256) void attn_kernel(
    const float* __restrict__ q,
    const float* __restrict__ mu,
    const float* __restrict__ iv,
    const float* __restrict__ alpha,
    const float* __restrict__ log_tau,
    float* __restrict__ wout)
{
    int l = blockIdx.x, h = blockIdx.y, b = blockIdx.z;
    int tid = threadIdx.x, lane = tid & 63, wid = tid >> 6;
    __shared__ float qs[D_S];
    __shared__ float eff_s[SL];
    float scale = -0.5f / expf(log_tau[0]);
    if (tid < D_S)
        qs[tid] = q[(long)(b*SL + l)*(NH*D_S) + h*D_S + tid];
    for (int j = tid; j < SL; j += 256) eff_s[j] = 0.f;
    __syncthreads();
    for (int j = wid; j <= l; j += 4) {
        const float* mup = mu + (long)(b*SL + j)*D_S;
        const float* ivp = iv + (long)(b*SL + j)*D_S;
        float t0 = qs[lane]      - mup[lane];
        float t1 = qs[lane + 64] - mup[lane + 64];
        float s = ivp[lane]*t0*t0 + ivp[lane + 64]*t1*t1;
        #pragma unroll
        for (int o = 32; o > 0; o >>= 1) s += __shfl_xor(s, o);
        if (lane == 0) {
            float Kv = expf(scale * s);
            float e  = fminf(alpha[b*SL + j] * Kv, 1.f - 1e-6f);
            eff_s[j] = e;
        }
    }
    __syncthreads();
    if (wid == 0) {
        float carry = 0.f;
        long orow = (((long)b*NH + h)*SL + l)*SL;
        for (int c = 0; c < SL/64; c++) {
            int j = c*64 + lane;
            float e  = eff_s[j];
            float le = log1pf(-e);
            float sc = le;
            #pragma unroll
            for (int o = 1; o < 64; o <<= 1) {
                float v = __shfl_up(sc, o);
                if (lane >= o) sc += v;
            }
            float logT = carry + sc - le;
            wout[orow + j] = e * expf(logT);
            carry += __shfl(sc, 63);
        }
    }
}

// ============================ x = concat(feats, meaning) ============================
__global__ __launch_bounds__(256) void build_x(
    const float* __restrict__ feats, const float* __restrict__ meaning,
    float* __restrict__ x)
{
    long i = (long)blockIdx.x*256 + threadIdx.x;
    if (i < (long)BL*D_F) {
        int r = (int)(i / D_F), c = (int)(i % D_F);
        x[(long)r*2*D_F + c]       = feats[i];
        x[(long)r*2*D_F + D_F + c] = meaning[i];
    }
}

// ============================ alpha gate ============================
__global__ __launch_bounds__(256) void gate_kernel(
    const float* __restrict__ x, const float* __restrict__ Wg,
    const float* __restrict__ bg, float* __restrict__ alpha)
{
    int r = blockIdx.x;
    int tid = threadIdx.x, lane = tid & 63, wid = tid >> 6;
    float s = 0.f;
    for (int c = tid; c < 2*D_F; c += 256)
        s += x[(long)r*2*D_F + c] * Wg[c];
    #pragma unroll
    for (int o = 32; o > 0; o >>= 1) s += __shfl_xor(s, o);
    __shared__ float red[4];
    if (lane == 0) red[wid] = s;
    __syncthreads();
    if (tid == 0) {
        float t = red[0] + red[1] + red[2] + red[3] + bg[0];
        alpha[r] *= 1.f / (1.f + expf(-t));
    }
}

// ============================ layernorm ============================
__global__ __launch_bounds__(256) void ln_kernel(
    const float* __restrict__ x, const float* __restrict__ g,
    const float* __restrict__ bsh, float* __restrict__ o, int D)
{
    int r = blockIdx.x;
    const float* xr = x + (long)r*D;
    int tid = threadIdx.x, lane = tid & 63, wid = tid >> 6;
    float s = 0.f, s2 = 0.f;
    for (int c = tid; c < D; c += 256) { float v = xr[c]; s += v; s2 += v*v; }
    #pragma unroll
    for (int o = 32; o > 0; o >>= 1) { s += __shfl_xor(s, o); s2 += __shfl_xor(s2, o); }
    __shared__ float rs[4], rs2[4], stat[2];
    if (lane == 0) { rs[wid] = s; rs2[wid] = s2; }
    __syncthreads();
    if (tid == 0) {
        float a = rs[0] + rs[1] + rs[2] + rs[3];
        float bb = rs2[0] + rs2[1] + rs2[2] + rs2[3];
        float mean = a / D;
        float var = bb / D - mean*mean;
        if (var < 0.f) var = 0.f;
        stat[0] = mean;
        stat[1] = 1.f / sqrtf(var + 1e-5f);
    }
    __syncthreads();
    float mean = stat[0], inv = stat[1];
    for (int c = tid; c < D; c += 256)
        o[(long)r*D + c] = (xr[c] - mean)*inv*g[c] + bsh[c];
}

// ============================ launch ============================
extern "C" void kernel_launch(void* const* d_in, const int* in_sizes, int n_in,
                              void* d_out, int out_size, void* d_ws, size_t ws_size,
                              hipStream_t stream)
{
    const int*   tokens  = (const int*)  d_in[0];
    const float* tok_mu  = (const float*)d_in[1];
    const float* tok_lv  = (const float*)d_in[2];
    const float* tok_ra  = (const float*)d_in[3];
    const float* tok_f   = (const float*)d_in[4];
    const float* pos_mu  = (const float*)d_in[5];
    const float* log_tau = (const float*)d_in[6];
    const float* Wq      = (const float*)d_in[7];
    const float* bq      = (const float*)d_in[8];
    const float* Whead   = (const float*)d_in[9];
    const float* bhead   = (const float*)d_in[10];
    const float* Wmu     = (const float*)d_in[11];
    const float* bmu     = (const float*)d_in[12];
    const float* Wg      = (const float*)d_in[13];
    const float* bg      = (const float*)d_in[14];
    const float* ln_g    = (const float*)d_in[15];
    const float* ln_b    = (const float*)d_in[16];
    const float* W1      = (const float*)d_in[17];
    const float* b1      = (const float*)d_in[18];
    const float* W2      = (const float*)d_in[19];
    const float* b2      = (const float*)d_in[20];
    const float* lnf_g   = (const float*)d_in[21];
    const float* lnf_b   = (const float*)d_in[22];
    const float* Wlm     = (const float*)d_in[23];
    float* out = (float*)d_out;

    // ---- workspace carve ----
    float* ws = (float*)d_ws;
    size_t off = 0;
    auto alloc = [&](size_t n) { float* p = ws + off; off += n; return p; };
    float* mu      = alloc((size_t)BL*D_S);
    float* iv      = alloc((size_t)BL*D_S);
    float* alpha   = alloc((size_t)BL);
    float* feats   = alloc((size_t)BL*D_F);
    float* q       = alloc((size_t)BL*NH*D_S);
    float* w       = alloc((size_t)NB*NH*SL*SL);   // also mahal S buffer
    float* mh      = alloc((size_t)BL*NH*D_F);
    float* meaning = alloc((size_t)BL*D_F);
    float* x       = alloc((size_t)BL*2*D_F);
    float* hbuf = w;
    float* y    = w;
    float* t    = mh;

    size_t offb = (off*sizeof(float) + 255) & ~(size_t)255;
    auto alloc16 = [&](size_t n) {
        u16* p = (u16*)((char*)d_ws + offb);
        offb = (offb + n*2 + 255) & ~(size_t)255;
        return p;
    };
    u16 *Ah     = alloc16((size_t)2048*4000), *Al     = alloc16((size_t)2048*4000);
    u16 *WqH    = alloc16((size_t)512*128),   *WqL    = alloc16((size_t)512*128);
    u16 *WheadH = alloc16((size_t)1024*4000), *WheadL = alloc16((size_t)1024*4000);
    u16 *WmuH   = alloc16((size_t)256*2016),  *WmuL   = alloc16((size_t)256*2016);
    u16 *W1H    = alloc16((size_t)2*4096*2016), *W1L  = alloc16((size_t)2*4096*2016);
    u16 *W2H    = alloc16((size_t)2*1024*4000), *W2L  = alloc16((size_t)2*1024*4000);
    u16 *WlmH   = alloc16((size_t)32000*1024),  *WlmL = alloc16((size_t)32000*1024);
    u16 *AeH    = alloc16((size_t)8192*288),  *AeL    = alloc16((size_t)8192*288);
    u16 *BeH    = alloc16((size_t)2048*288),  *BeL    = alloc16((size_t)2048*288);
    u16 *wH     = alloc16((size_t)8192*512),  *wL     = alloc16((size_t)8192*512);
    u16 *fTH    = alloc16((size_t)4*1024*512),*fTL    = alloc16((size_t)4*1024*512);
    const bool use_mfma = ws_size >= offb;

    auto SPL = [&](const float* W_, u16* H_, u16* L_, int N_, int K_, int Np_, int Kp_) {
        long t4 = (long)Np_ * Kp_ / 4;
        int nb = (int)((t4 + 255) / 256);
        if (nb > 2048) nb = 2048;
        split_hl<<<nb, 256, 0, stream>>>(W_, H_, L_, N_, K_, Np_, Kp_);
    };
    auto ASPL = [&](const float* A_, int K_, int Kp_) {
        long t4 = (long)2048 * Kp_ / 4;
        int nb = (int)((t4 + 255) / 256);
        if (nb > 2048) nb = 2048;
        split_hl<<<nb, 256, 0, stream>>>(A_, Ah, Al, 2048, K_, 2048, Kp_);
    };

    gather_kernel<<<BL, 256, 0, stream>>>(tokens, tok_mu, tok_lv, tok_ra, tok_f,
                                          pos_mu, mu, iv, alpha, feats);

    if (use_mfma) {
        // one-time weight splits
        SPL(Wq,    WqH,    WqL,    512,   128,  512,   128);
        SPL(Whead, WheadH, WheadL, 1000,  4000, 1024,  4000);
        SPL(Wmu,   WmuH,   WmuL,   256,   2000, 256,   2016);
        for (int p = 0; p < 2; p++) {
            SPL(W1 + (size_t)p*4000*2000, W1H + (size_t)p*4096*2016,
                W1L + (size_t)p*4096*2016, 4000, 2000, 4096, 2016);
            SPL(W2 + (size_t)p*1000*4000, W2H + (size_t)p*1024*4000,
                W2L + (size_t)p*1024*4000, 1000, 4000, 1024, 4000);
        }
        SPL(Wlm, WlmH, WlmL, 32000, 1000, 32000, 1024);

        for (int p = 0; p < NP; p++) {
            // q = mu @ Wq.T + bq
            ASPL(mu, 128, 128);
            gemm_bf3<1><<<dim3(4, 16), 256, 0, stream>>>(Ah, Al, WqH, WqL, bq, q,
                                                         BL, NH*D_S, 128);
            // mahal via MFMA: build extended operands, GEMM, scan
            build_a_ext<<<8192, 256, 0, stream>>>(q, AeH, AeL);
            build_b_ext<<<2048, 256, 0, stream>>>(mu, iv, BeH, BeL);
            gemm_mahal<<<dim3(4, 4, 16), 256, 0, stream>>>(AeH, AeL, BeH, BeL, w);
            scan_kernel<<<2048, 256, 0, stream>>>(w, alpha, log_tau);
            // mh = w @ feats via MFMA
            SPL(w, wH, wL, 8192, 512, 8192, 512);
            tsplit_feats<<<dim3(32, 16, NB), 256, 0, stream>>>(feats, fTH, fTL);
            gemm_mh_bf3<<<dim3(8, 16, NB), 256, 0, stream>>>(wH, wL, fTH, fTL, mh);
            // meaning = mh @ Whead.T + bhead
            ASPL(mh, 4000, 4000);
            gemm_bf3<1><<<dim3(8, 16), 256, 0, stream>>>(Ah, Al, WheadH, WheadL, bhead,
                                                         meaning, BL, D_F, 4000);
            if (p < NP - 1) {
                build_x<<<(BL*D_F + 255)/256, 256, 0, stream>>>(feats, meaning, x);
                gate_kernel<<<BL, 256, 0, stream>>>(x, Wg + (size_t)p*2*D_F, bg + p, alpha);
                ASPL(x, 2000, 2016);
                gemm_bf3<4><<<dim3(1, 16), 256, 0, stream>>>(
                    Ah, Al, WmuH + (size_t)p*128*2016, WmuL + (size_t)p*128*2016,
                    bmu + (size_t)p*D_S, mu, BL, D_S, 2016);
                ln_kernel<<<BL, 256, 0, stream>>>(x, ln_g + (size_t)p*2*D_F,
                                                  ln_b + (size_t)p*2*D_F, hbuf, 2*D_F);
                ASPL(hbuf, 2000, 2016);
                gemm_bf3<2><<<dim3(32, 16), 256, 0, stream>>>(
                    Ah, Al, W1H + (size_t)p*4096*2016, W1L + (size_t)p*4096*2016,
                    b1 + (size_t)p*4*D_F, t, BL, 4*D_F, 2016);
                ASPL(t, 4000, 4000);
                gemm_bf3<3><<<dim3(8, 16), 256, 0, stream>>>(
                    Ah, Al, W2H + (size_t)p*1024*4000, W2L + (size_t)p*1024*4000,
                    b2 + (size_t)p*D_F, feats, BL, D_F, 4000);
            }
        }
        ln_kernel<<<BL, 256, 0, stream>>>(meaning, lnf_g, lnf_b, y, D_F);
        ASPL(y, 1000, 1024);
        gemm_bf3<0><<<dim3(250, 16), 256, 0, stream>>>(Ah, Al, WlmH, WlmL, nullptr, out,
                                                       BL, 32000, 1024);
    } else {
        // ---- fp32 fallback ----
        for (int p = 0; p < NP; p++) {
            gemm_tn<1><<<dim3(8, 32), 256, 0, stream>>>(mu, Wq, bq, q, BL, NH*D_S, D_S);
            attn_kernel<<<dim3(SL, NH, NB), 256, 0, stream>>>(q, mu, iv, alpha, log_tau, w);
            gemm_mh<<<dim3(16, 32, NB), 256, 0, stream>>>(w, feats, mh);
            gemm_tn<1><<<dim3(16, 32), 256, 0, stream>>>(mh, Whead, bhead, meaning, BL, D_F, NH*D_F);
            if (p < NP - 1) {
                build_x<<<(BL*D_F + 255)/256, 256, 0, stream>>>(feats, meaning, x);
                gate_kernel<<<BL, 256, 0, stream>>>(x, Wg + (size_t)p*2*D_F, bg + p, alpha);
                gemm_tn<4><<<dim3(2, 32), 256, 0, stream>>>(x, Wmu + (size_t)p*D_S*2*D_F,
                                                            bmu + (size_t)p*D_S, mu, BL, D_S, 2*D_F);
                ln_kernel<<<BL, 256, 0, stream>>>(x, ln_g + (size_t)p*2*D_F, ln_b + (size_t)p*2*D_F,
                                                  hbuf, 2*D_F);
                gemm_tn<2><<<dim3(63, 32), 256, 0, stream>>>(hbuf, W1 + (size_t)p*4*D_F*2*D_F,
                                                             b1 + (size_t)p*4*D_F, t, BL, 4*D_F, 2*D_F);
                gemm_tn<3><<<dim3(16, 32), 256, 0, stream>>>(t, W2 + (size_t)p*D_F*4*D_F,
                                                             b2 + (size_t)p*D_F, feats, BL, D_F, 4*D_F);
            }
        }
        ln_kernel<<<BL, 256, 0, stream>>>(meaning, lnf_g, lnf_b, y, D_F);
        gemm_tn<0><<<dim3(500, 32), 256, 0, stream>>>(y, Wlm, nullptr, out, BL, 32000, D_F);
    }
}

// Round 3
// 2902.540 us; speedup vs baseline: 3.3972x; 1.0045x over previous
//
#include <hip/hip_runtime.h>

#define D_S 128
#define D_F 1000
#define NH  4
#define NP  3
#define NB  4
#define SL  512
#define BL  (NB*SL)   // 2048 token rows

typedef unsigned short u16;
typedef unsigned int   u32;

using short8 = __attribute__((ext_vector_type(8))) short;  // 8 bf16 (4 VGPRs)
using f32x4  = __attribute__((ext_vector_type(4))) float;  // MFMA C/D

// ============================ gather ============================
__global__ __launch_bounds__(256) void gather_kernel(
    const int* __restrict__ tokens, const float* __restrict__ tok_mu,
    const float* __restrict__ tok_lv, const float* __restrict__ tok_ra,
    const float* __restrict__ tok_f, const float* __restrict__ pos_mu,
    float* __restrict__ mu, float* __restrict__ iv,
    float* __restrict__ alpha, float* __restrict__ feats)
{
    int row = blockIdx.x;            // b*SL + l
    int l = row & (SL - 1);
    int tok = tokens[row];
    for (int d = threadIdx.x; d < D_S; d += 256) {
        mu[row*D_S + d] = tok_mu[tok*D_S + d] + pos_mu[l*D_S + d];
        iv[row*D_S + d] = expf(-tok_lv[tok*D_S + d]);
    }
    if (threadIdx.x == 0)
        alpha[row] = 1.f / (1.f + expf(-tok_ra[tok]));
    for (int f = threadIdx.x; f < D_F; f += 256)
        feats[row*D_F + f] = tok_f[tok*D_F + f];
}

// ============================ fp32 -> bf16 hi/lo split helpers ============================
__device__ __forceinline__ void split1(float v, u16* __restrict__ H,
                                       u16* __restrict__ L, long idx)
{
    u32 b = __float_as_uint(v);
    H[idx] = (u16)(b >> 16);
    float r = v - __uint_as_float(b & 0xffff0000u);
    u32 br = __float_as_uint(r);
    L[idx] = (u16)((br + 0x7fffu + ((br >> 16) & 1u)) >> 16);
}

__global__ __launch_bounds__(256) void split_hl(
    const float* __restrict__ src, u16* __restrict__ H, u16* __restrict__ L,
    int N, int K, int Np, int Kp)
{
    long total4 = (long)Np * Kp / 4;
    for (long i = (long)blockIdx.x * 256 + threadIdx.x; i < total4;
         i += (long)gridDim.x * 256) {
        long i4 = i * 4;
        int n = (int)(i4 / Kp);
        int k = (int)(i4 - (long)n * Kp);
        float v[4];
        if (n < N && k + 3 < K) {
            const float4 t = *(const float4*)(src + (long)n * K + k);
            v[0] = t.x; v[1] = t.y; v[2] = t.z; v[3] = t.w;
        } else {
            #pragma unroll
            for (int j = 0; j < 4; j++)
                v[j] = (n < N && k + j < K) ? src[(long)n * K + k + j] : 0.f;
        }
        u32 hh[4], ll[4];
        #pragma unroll
        for (int j = 0; j < 4; j++) {
            u32 b = __float_as_uint(v[j]);
            hh[j] = b >> 16;
            float r = v[j] - __uint_as_float(b & 0xffff0000u);
            u32 br = __float_as_uint(r);
            ll[j] = (br + 0x7fffu + ((br >> 16) & 1u)) >> 16;
        }
        uint2 hp, lp;
        hp.x = hh[0] | (hh[1] << 16); hp.y = hh[2] | (hh[3] << 16);
        lp.x = ll[0] | (ll[1] << 16); lp.y = ll[2] | (ll[3] << 16);
        *(uint2*)(H + i4) = hp;
        *(uint2*)(L + i4) = lp;
    }
}

// Aext tail: cols [256,288) of every row are the constant [1, 0...0]
__global__ __launch_bounds__(256) void aext_tail(u16* __restrict__ H, u16* __restrict__ L)
{
    long i = (long)blockIdx.x*256 + threadIdx.x;   // 8192*32
    if (i < (long)8192*32) {
        int row = (int)(i >> 5), t = (int)(i & 31);
        long o = (long)row*288 + 256 + t;
        H[o] = (t == 0) ? 0x3f80 : 0;
        L[o] = 0;
    }
}

// ============================ MFMA bf16x3 TN GEMM ============================
__device__ __forceinline__ void gl_lds16(const u16* g, u16* l) {
    __builtin_amdgcn_global_load_lds(
        (const __attribute__((address_space(1))) void*)g,
        (__attribute__((address_space(3))) void*)l, 16, 0, 0);
}

// C[M,N] = A[M,Kp] @ Bt[N,Kp]^T, bf16 hi/lo pairs, 3-MFMA fp32-equivalent.
// 128x128 tile, BK=32, 4 waves (2x2). M-inner + XCD swizzle (nwg%8==0).
// EPI: 0=store, 1=+bias, 3=C+=(+bias), 4=C+=tanh(+bias),
//      5=split-store gelu(+bias) to OH/OL (stride N),
//      6=q epilogue: write Aext rows [q^2 (d), q (128+d)] to OH/OL (no C).
template<int EPI>
__global__ __launch_bounds__(256, 2) void gemm_bf3(
    const u16* __restrict__ Ah, const u16* __restrict__ Al,
    const u16* __restrict__ Bh, const u16* __restrict__ Bl,
    const float* __restrict__ bias, float* __restrict__ C,
    u16* __restrict__ OH, u16* __restrict__ OL,
    int M, int N, int Kp)
{
    __shared__ u16 sAh[128*32], sAl[128*32], sBh[128*32], sBl[128*32];
    const int tid = threadIdx.x;
    const int lane = tid & 63, wid = tid >> 6;
    const int wr = wid >> 1, wc = wid & 1;

    const int nmt = gridDim.y;
    const int nwg = gridDim.x * nmt;
    const int bid = blockIdx.y * gridDim.x + blockIdx.x;
    const int work = (bid & 7) * (nwg >> 3) + (bid >> 3);
    const int bm = (work % nmt) * 128;
    const int bn = (work / nmt) * 128;

    f32x4 acc[4][4];
    const f32x4 z = {0.f, 0.f, 0.f, 0.f};
    #pragma unroll
    for (int i = 0; i < 4; i++)
        #pragma unroll
        for (int j = 0; j < 4; j++) acc[i][j] = z;

    const int nkt = Kp >> 5;
    const int kg = (lane >> 4) << 3;
    const int ar = (wr << 6) + (lane & 15);
    const int br = (wc << 6) + (lane & 15);

    for (int kt = 0; kt < nkt; ++kt) {
        const int kk = kt << 5;
        #pragma unroll
        for (int c = 0; c < 2; ++c) {
            int i   = c * 256 + tid;
            int row = i >> 2;
            int kq  = (i & 3) << 3;
            long ga = (long)(bm + row) * Kp + kk + kq;
            long gb = (long)(bn + row) * Kp + kk + kq;
            int  le = i << 3;
            gl_lds16(Ah + ga, sAh + le);
            gl_lds16(Al + ga, sAl + le);
            gl_lds16(Bh + gb, sBh + le);
            gl_lds16(Bl + gb, sBl + le);
        }
        __syncthreads();

        short8 a_h[4], a_l[4], b_h[4], b_l[4];
        #pragma unroll
        for (int t = 0; t < 4; ++t) {
            a_h[t] = *(const short8*)&sAh[(ar + t*16)*32 + kg];
            a_l[t] = *(const short8*)&sAl[(ar + t*16)*32 + kg];
            b_h[t] = *(const short8*)&sBh[(br + t*16)*32 + kg];
            b_l[t] = *(const short8*)&sBl[(br + t*16)*32 + kg];
        }
        #pragma unroll
        for (int mi = 0; mi < 4; ++mi)
            #pragma unroll
            for (int ni = 0; ni < 4; ++ni) {
                f32x4 cacc = acc[mi][ni];
                cacc = __builtin_amdgcn_mfma_f32_16x16x32_bf16(a_h[mi], b_h[ni], cacc, 0, 0, 0);
                cacc = __builtin_amdgcn_mfma_f32_16x16x32_bf16(a_l[mi], b_h[ni], cacc, 0, 0, 0);
                cacc = __builtin_amdgcn_mfma_f32_16x16x32_bf16(a_h[mi], b_l[ni], cacc, 0, 0, 0);
                acc[mi][ni] = cacc;
            }
        __syncthreads();
    }

    const int r0 = bm + (wr << 6) + ((lane >> 4) << 2);
    const int c0 = bn + (wc << 6) + (lane & 15);
    #pragma unroll
    for (int mi = 0; mi < 4; ++mi) {
        #pragma unroll
        for (int ni = 0; ni < 4; ++ni) {
            int cg = c0 + ni * 16;
            if (cg >= N) continue;
            float bv = (EPI == 0) ? 0.f : bias[cg];
            #pragma unroll
            for (int r = 0; r < 4; ++r) {
                int rg = r0 + mi * 16 + r;
                long idx = (long)rg * N + cg;
                float v = acc[mi][ni][r];
                if (EPI == 0)      C[idx] = v;
                else if (EPI == 1) C[idx] = v + bv;
                else if (EPI == 3) C[idx] += v + bv;
                else if (EPI == 4) C[idx] += tanhf(v + bv);
                else if (EPI == 5) {
                    float u = v + bv;
                    float gl = 0.5f*u*(1.f + erff(u*0.70710678118654752f));
                    split1(gl, OH, OL, idx);
                }
                else if (EPI == 6) {
                    float qv = v + bv;
                    int b = rg >> 9, l = rg & 511, h = cg >> 7, d = cg & 127;
                    long base = ((long)((b << 2) | h) * 512 + l) * 288;
                    split1(qv*qv, OH, OL, base + d);
                    split1(qv,    OH, OL, base + 128 + d);
                }
            }
        }
    }
}

// ============================ mahalanobis as MFMA GEMM ============================
__global__ __launch_bounds__(256, 2) void gemm_mahal(
    const u16* __restrict__ Ah, const u16* __restrict__ Al,
    const u16* __restrict__ Bh, const u16* __restrict__ Bl,
    float* __restrict__ S)
{
    const int KP = 288;
    __shared__ u16 sAh[128*32], sAl[128*32], sBh[128*32], sBl[128*32];
    const int bmi = blockIdx.y, bni = blockIdx.x;
    if (bni > bmi) return;
    const int tid = threadIdx.x;
    const int lane = tid & 63, wid = tid >> 6;
    const int wr = wid >> 1, wc = wid & 1;
    const int bh = blockIdx.z;
    const long arow0 = (long)bh * 512 + bmi * 128;
    const long brow0 = (long)(bh >> 2) * 512 + bni * 128;

    f32x4 acc[4][4];
    const f32x4 z = {0.f, 0.f, 0.f, 0.f};
    #pragma unroll
    for (int i = 0; i < 4; i++)
        #pragma unroll
        for (int j = 0; j < 4; j++) acc[i][j] = z;

    const int kg = (lane >> 4) << 3;
    const int ar = (wr << 6) + (lane & 15);
    const int br = (wc << 6) + (lane & 15);

    for (int kt = 0; kt < 9; ++kt) {
        const int kk = kt << 5;
        #pragma unroll
        for (int c = 0; c < 2; ++c) {
            int i   = c * 256 + tid;
            int row = i >> 2;
            int kq  = (i & 3) << 3;
            long ga = (arow0 + row) * KP + kk + kq;
            long gb = (brow0 + row) * KP + kk + kq;
            int  le = i << 3;
            gl_lds16(Ah + ga, sAh + le);
            gl_lds16(Al + ga, sAl + le);
            gl_lds16(Bh + gb, sBh + le);
            gl_lds16(Bl + gb, sBl + le);
        }
        __syncthreads();
        short8 a_h[4], a_l[4], b_h[4], b_l[4];
        #pragma unroll
        for (int t = 0; t < 4; ++t) {
            a_h[t] = *(const short8*)&sAh[(ar + t*16)*32 + kg];
            a_l[t] = *(const short8*)&sAl[(ar + t*16)*32 + kg];
            b_h[t] = *(const short8*)&sBh[(br + t*16)*32 + kg];
            b_l[t] = *(const short8*)&sBl[(br + t*16)*32 + kg];
        }
        #pragma unroll
        for (int mi = 0; mi < 4; ++mi)
            #pragma unroll
            for (int ni = 0; ni < 4; ++ni) {
                f32x4 cacc = acc[mi][ni];
                cacc = __builtin_amdgcn_mfma_f32_16x16x32_bf16(a_h[mi], b_h[ni], cacc, 0, 0, 0);
                cacc = __builtin_amdgcn_mfma_f32_16x16x32_bf16(a_l[mi], b_h[ni], cacc, 0, 0, 0);
                cacc = __builtin_amdgcn_mfma_f32_16x16x32_bf16(a_h[mi], b_l[ni], cacc, 0, 0, 0);
                acc[mi][ni] = cacc;
            }
        __syncthreads();
    }

    const int r0 = bmi * 128 + (wr << 6) + ((lane >> 4) << 2);
    const int c0 = bni * 128 + (wc << 6) + (lane & 15);
    #pragma unroll
    for (int mi = 0; mi < 4; ++mi)
        #pragma unroll
        for (int ni = 0; ni < 4; ++ni) {
            int cg = c0 + ni * 16;
            #pragma unroll
            for (int r = 0; r < 4; ++r) {
                int rg = r0 + mi * 16 + r;
                S[((long)bh * 512 + rg) * 512 + cg] = acc[mi][ni][r];
            }
        }
}

// Bext[b*512+j] = [iv (128), -2*mu*iv (128), sum(mu^2*iv), 0...]
__global__ __launch_bounds__(256) void build_b_ext(
    const float* __restrict__ mu, const float* __restrict__ iv,
    u16* __restrict__ H, u16* __restrict__ L)
{
    int row = blockIdx.x;            // b*SL + j
    int tid = threadIdx.x, lane = tid & 63;
    const float* mup = mu + (long)row*D_S;
    const float* ivp = iv + (long)row*D_S;
    __shared__ float red[2];
    float part = 0.f;
    if (tid < 128) { float m = mup[tid]; part = m*m*ivp[tid]; }
    #pragma unroll
    for (int o = 32; o > 0; o >>= 1) part += __shfl_xor(part, o);
    if (tid < 128 && lane == 0) red[tid >> 6] = part;
    __syncthreads();
    float mu2 = red[0] + red[1];
    long base = (long)row * 288;
    for (int t = tid; t < 288; t += 256) {
        float v;
        if (t < 128)        v = ivp[t];
        else if (t < 256)   v = -2.f * mup[t-128] * ivp[t-128];
        else if (t == 256)  v = mu2;
        else                v = 0.f;
        split1(v, H, L, base + t);
    }
}

// ============================ compositing scan: S -> split(w) ============================
__global__ __launch_bounds__(256) void scan_kernel(
    const float* __restrict__ S, const float* __restrict__ alpha,
    const float* __restrict__ log_tau,
    u16* __restrict__ WH, u16* __restrict__ WL)
{
    int row = blockIdx.x * 4 + (threadIdx.x >> 6);   // bh*512 + l
    int lane = threadIdx.x & 63;
    int b = row >> 11, l = row & 511;
    float scale = -0.5f * expf(-log_tau[0]);
    long base = (long)row * 512;
    float carry = 0.f;
    for (int c = 0; c < 8; c++) {
        int j = c*64 + lane;
        float e = 0.f;
        if (j <= l) {
            float Kv = expf(scale * S[base + j]);
            e = fminf(alpha[b*SL + j] * Kv, 1.f - 1e-6f);
        }
        float le = log1pf(-e);
        float sc = le;
        #pragma unroll
        for (int o = 1; o < 64; o <<= 1) {
            float v = __shfl_up(sc, o);
            if (lane >= o) sc += v;
        }
        float logT = carry + sc - le;
        split1(e * expf(logT), WH, WL, base + j);
        carry += __shfl(sc, 63);
    }
}

// ============================ feats transpose + split ============================
__global__ __launch_bounds__(256) void tsplit_feats(
    const float* __restrict__ feats, u16* __restrict__ H, u16* __restrict__ L)
{
    __shared__ float tile[32][33];
    int b = blockIdx.z, f0 = blockIdx.x*32, j0 = blockIdx.y*32;
    int tx = threadIdx.x & 31, ty = threadIdx.x >> 5;   // 32 x 8
    #pragma unroll
    for (int i = 0; i < 4; i++) {
        int j = j0 + ty + 8*i, f = f0 + tx;
        tile[ty + 8*i][tx] = (f < D_F) ? feats[(long)(b*SL + j)*D_F + f] : 0.f;
    }
    __syncthreads();
    #pragma unroll
    for (int i = 0; i < 4; i++) {
        int f = f0 + ty + 8*i, j = j0 + tx;
        split1(tile[tx][ty + 8*i], H, L, ((long)(b*1024 + f))*512 + j);
    }
}

// ============================ mh = w @ feats via MFMA (split-store) ============================
__global__ __launch_bounds__(256, 2) void gemm_mh_bf3(
    const u16* __restrict__ Ah, const u16* __restrict__ Al,
    const u16* __restrict__ Bh, const u16* __restrict__ Bl,
    u16* __restrict__ OH, u16* __restrict__ OL)
{
    const int KP = 512;
    __shared__ u16 sAh[128*32], sAl[128*32], sBh[128*32], sBl[128*32];
    const int tid = threadIdx.x;
    const int lane = tid & 63, wid = tid >> 6;
    const int wr = wid >> 1, wc = wid & 1;
    const int b = blockIdx.z;
    const int bm = blockIdx.y * 128;       // h*512+l
    const int bn = blockIdx.x * 128;       // f
    const long arow0 = (long)b*2048 + bm;
    const long brow0 = (long)b*1024 + bn;
    const int kmax = (bm & 511) + 128;
    const int nkt = kmax >> 5;

    f32x4 acc[4][4];
    const f32x4 z = {0.f, 0.f, 0.f, 0.f};
    #pragma unroll
    for (int i = 0; i < 4; i++)
        #pragma unroll
        for (int j = 0; j < 4; j++) acc[i][j] = z;

    const int kg = (lane >> 4) << 3;
    const int ar = (wr << 6) + (lane & 15);
    const int br = (wc << 6) + (lane & 15);

    for (int kt = 0; kt < nkt; ++kt) {
        const int kk = kt << 5;
        #pragma unroll
        for (int c = 0; c < 2; ++c) {
            int i   = c * 256 + tid;
            int row = i >> 2;
            int kq  = (i & 3) << 3;
            long ga = (arow0 + row) * KP + kk + kq;
            long gb = (brow0 + row) * KP + kk + kq;
            int  le = i << 3;
            gl_lds16(Ah + ga, sAh + le);
            gl_lds16(Al + ga, sAl + le);
            gl_lds16(Bh + gb, sBh + le);
            gl_lds16(Bl + gb, sBl + le);
        }
        __syncthreads();
        short8 a_h[4], a_l[4], b_h[4], b_l[4];
        #pragma unroll
        for (int t = 0; t < 4; ++t) {
            a_h[t] = *(const short8*)&sAh[(ar + t*16)*32 + kg];
            a_l[t] = *(const short8*)&sAl[(ar + t*16)*32 + kg];
            b_h[t] = *(const short8*)&sBh[(br + t*16)*32 + kg];
            b_l[t] = *(const short8*)&sBl[(br + t*16)*32 + kg];
        }
        #pragma unroll
        for (int mi = 0; mi < 4; ++mi)
            #pragma unroll
            for (int ni = 0; ni < 4; ++ni) {
                f32x4 cacc = acc[mi][ni];
                cacc = __builtin_amdgcn_mfma_f32_16x16x32_bf16(a_h[mi], b_h[ni], cacc, 0, 0, 0);
                cacc = __builtin_amdgcn_mfma_f32_16x16x32_bf16(a_l[mi], b_h[ni], cacc, 0, 0, 0);
                cacc = __builtin_amdgcn_mfma_f32_16x16x32_bf16(a_h[mi], b_l[ni], cacc, 0, 0, 0);
                acc[mi][ni] = cacc;
            }
        __syncthreads();
    }

    const int r0 = bm + (wr << 6) + ((lane >> 4) << 2);
    const int c0 = bn + (wc << 6) + (lane & 15);
    #pragma unroll
    for (int mi = 0; mi < 4; ++mi) {
        #pragma unroll
        for (int ni = 0; ni < 4; ++ni) {
            int cg = c0 + ni * 16;
            if (cg >= D_F) continue;
            #pragma unroll
            for (int r = 0; r < 4; ++r) {
                int rg = r0 + mi * 16 + r;      // h*512+l
                int h = rg >> 9, l = rg & 511;
                split1(acc[mi][ni][r], OH, OL,
                       ((long)(b*SL + l)*NH + h)*D_F + cg);
            }
        }
    }
}

// ============ fused: x=concat(feats,meaning); gate; LN; split x and h ============
__global__ __launch_bounds__(256) void fuse_xgl(
    const float* __restrict__ feats, const float* __restrict__ meaning,
    const float* __restrict__ Wg, const float* __restrict__ bg,
    float* __restrict__ alpha,
    const float* __restrict__ g, const float* __restrict__ bsh,
    u16* __restrict__ XH, u16* __restrict__ XL,
    u16* __restrict__ HH, u16* __restrict__ HL)
{
    int r = blockIdx.x;
    int tid = threadIdx.x, lane = tid & 63, wid = tid >> 6;
    __shared__ float xs[2*D_F];
    __shared__ float rd[4], rs[4], rs2[4], stat[2];
    for (int c = tid; c < D_F; c += 256) {
        xs[c]       = feats[(long)r*D_F + c];
        xs[D_F + c] = meaning[(long)r*D_F + c];
    }
    __syncthreads();
    float dot = 0.f, s = 0.f, s2 = 0.f;
    for (int c = tid; c < 2*D_F; c += 256) {
        float v = xs[c];
        dot += v * Wg[c]; s += v; s2 += v*v;
    }
    #pragma unroll
    for (int o = 32; o > 0; o >>= 1) {
        dot += __shfl_xor(dot, o); s += __shfl_xor(s, o); s2 += __shfl_xor(s2, o);
    }
    if (lane == 0) { rd[wid] = dot; rs[wid] = s; rs2[wid] = s2; }
    __syncthreads();
    if (tid == 0) {
        float d4 = rd[0]+rd[1]+rd[2]+rd[3] + bg[0];
        alpha[r] *= 1.f / (1.f + expf(-d4));
        float a  = rs[0]+rs[1]+rs[2]+rs[3];
        float bb = rs2[0]+rs2[1]+rs2[2]+rs2[3];
        float mean = a / (2*D_F);
        float var = bb / (2*D_F) - mean*mean;
        if (var < 0.f) var = 0.f;
        stat[0] = mean;
        stat[1] = 1.f / sqrtf(var + 1e-5f);
    }
    __syncthreads();
    float mean = stat[0], inv = stat[1];
    for (int c = tid; c < 2016; c += 256) {
        long o = (long)r*2016 + c;
        if (c < 2*D_F) {
            float v = xs[c];
            split1(v, XH, XL, o);
            float h = (v - mean)*inv*g[c] + bsh[c];
            split1(h, HH, HL, o);
        } else {
            XH[o] = 0; XL[o] = 0; HH[o] = 0; HL[o] = 0;
        }
    }
}

// ============================ LN with split output ============================
__global__ __launch_bounds__(256) void ln_split(
    const float* __restrict__ x, const float* __restrict__ g,
    const float* __restrict__ bsh, u16* __restrict__ OH, u16* __restrict__ OL,
    int D, int Kp)
{
    int r = blockIdx.x;
    const float* xr = x + (long)r*D;
    int tid = threadIdx.x, lane = tid & 63, wid = tid >> 6;
    float s = 0.f, s2 = 0.f;
    for (int c = tid; c < D; c += 256) { float v = xr[c]; s += v; s2 += v*v; }
    #pragma unroll
    for (int o = 32; o > 0; o >>= 1) { s += __shfl_xor(s, o); s2 += __shfl_xor(s2, o); }
    __shared__ float rs[4], rs2[4], stat[2];
    if (lane == 0) { rs[wid] = s; rs2[wid] = s2; }
    __syncthreads();
    if (tid == 0) {
        float a = rs[0]+rs[1]+rs[2]+rs[3];
        float bb = rs2[0]+rs2[1]+rs2[2]+rs2[3];
        float mean = a / D;
        float var = bb / D - mean*mean;
        if (var < 0.f) var = 0.f;
        stat[0] = mean;
        stat[1] = 1.f / sqrtf(var + 1e-5f);
    }
    __syncthreads();
    float mean = stat[0], inv = stat[1];
    for (int c = tid; c < Kp; c += 256) {
        long o = (long)r*Kp + c;
        if (c < D) split1((xr[c] - mean)*inv*g[c] + bsh[c], OH, OL, o);
        else       { OH[o] = 0; OL[o] = 0; }
    }
}

// ============================ fp32 fallback kernels ============================
template<int EPI>
__global__ __launch_bounds__(256) void gemm_tn(
    const float* __restrict__ A, const float* __restrict__ Bt,
    const float* __restrict__ bias, float* __restrict__ C,
    int M, int N, int K)
{
    const int BM = 64, BN = 64, BK = 16;
    __shared__ float As[BK][BM + 4];
    __shared__ float Bs[BK][BN + 4];
    int tid = threadIdx.x;
    int tx = tid & 15, ty = tid >> 4;
    int bm = blockIdx.y * BM, bn = blockIdx.x * BN;
    int lr = tid >> 2;
    int lk = (tid & 3) * 4;
    float acc[4][4] = {};
    for (int kk = 0; kk < K; kk += BK) {
        int gr = bm + lr;
        int gn = bn + lr;
        #pragma unroll
        for (int i = 0; i < 4; i++) {
            int gk = kk + lk + i;
            As[lk + i][lr] = (gr < M && gk < K) ? A[(long)gr*K + gk] : 0.f;
            Bs[lk + i][lr] = (gn < N && gk < K) ? Bt[(long)gn*K + gk] : 0.f;
        }
        __syncthreads();
        #pragma unroll
        for (int k = 0; k < BK; k++) {
            float4 av = *(const float4*)&As[k][ty << 2];
            float4 bv = *(const float4*)&Bs[k][tx << 2];
            float a[4] = {av.x, av.y, av.z, av.w};
            float b[4] = {bv.x, bv.y, bv.z, bv.w};
            #pragma unroll
            for (int i = 0; i < 4; i++)
                #pragma unroll
                for (int j = 0; j < 4; j++)
                    acc[i][j] += a[i] * b[j];
        }
        __syncthreads();
    }
    #pragma unroll
    for (int i = 0; i < 4; i++) {
        int r = bm + (ty << 2) + i;
        if (r >= M) continue;
        #pragma unroll
        for (int j = 0; j < 4; j++) {
            int c = bn + (tx << 2) + j;
            if (c >= N) continue;
            float v = acc[i][j];
            long idx = (long)r*N + c;
            if (EPI == 0)      C[idx] = v;
            else if (EPI == 1) C[idx] = v + bias[c];
            else if (EPI == 2) { v += bias[c]; C[idx] = 0.5f*v*(1.f + erff(v*0.70710678118654752f)); }
            else if (EPI == 3) C[idx] += v + bias[c];
            else if (EPI == 4) C[idx] += tanhf(v + bias[c]);
        }
    }
}

__global__ __launch_bounds__(256) void gemm_mh(
    const float* __restrict__ Wfull, const float* __restrict__ feats,
    float* __restrict__ mh)
{
    const int BM = 64, BN = 64, BK = 16;
    const int M = NH*SL, N = D_F, K = SL;
    __shared__ float As[BK][BM + 4];
    __shared__ float Bs[BK][BN + 4];
    int b = blockIdx.z;
    const float* A  = Wfull + (long)b*M*K;
    const float* Bm = feats + (long)b*SL*D_F;
    int tid = threadIdx.x;
    int tx = tid & 15, ty = tid >> 4;
    int bm = blockIdx.y * BM, bn = blockIdx.x * BN;
    int kmax = (bm & (SL - 1)) + BM;
    int lrA = tid >> 2, lkA = (tid & 3) * 4;
    int lkB = tid >> 4, lnB = (tid & 15) * 4;
    float acc[4][4] = {};
    for (int kk = 0; kk < kmax; kk += BK) {
        #pragma unroll
        for (int i = 0; i < 4; i++)
            As[lkA + i][lrA] = A[(long)(bm + lrA)*K + kk + lkA + i];
        #pragma unroll
        for (int j = 0; j < 4; j++) {
            int gn = bn + lnB + j;
            Bs[lkB][lnB + j] = (gn < N) ? Bm[(long)(kk + lkB)*N + gn] : 0.f;
        }
        __syncthreads();
        #pragma unroll
        for (int k = 0; k < BK; k++) {
            float4 av = *(const float4*)&As[k][ty << 2];
            float4 bv = *(const float4*)&Bs[k][tx << 2];
            float a[4] = {av.x, av.y, av.z, av.w};
            float bb[4] = {bv.x, bv.y, bv.z, bv.w};
            #pragma unroll
            for (int i = 0; i < 4; i++)
                #pragma unroll
                for (int j = 0; j < 4; j++)
                    acc[i][j] += a[i] * bb[j];
        }
        __syncthreads();
    }
    int h = bm / SL;
    #pragma unroll
    for (int i = 0; i < 4; i++) {
        int r = bm + (ty << 2) + i;
        int l = r & (SL - 1);
        long orow = ((long)(b*SL + l)*NH + h) * D_F;
        #pragma unroll
        for (int j = 0; j < 4; j++) {
            int c = bn + (tx << 2) + j;
            if (c < N) mh[orow + c] = acc[i][j];
        }
    }
}

__global__ __launch_bounds__(256) void attn_kernel(
    const float* __restrict__ q,
    const float* __restrict__ mu,
    const float* __restrict__ iv,
    const float* __restrict__ alpha,
    const float* __restrict__ log_tau,
    float* __restrict__ wout)
{
    int l = blockIdx.x, h = blockIdx.y, b = blockIdx.z;
    int tid = threadIdx.x, lane = tid & 63, wid = tid >> 6;
    __shared__ float qs[D_S];
    __shared__ float eff_s[SL];
    float scale = -0.5f / expf(log_tau[0]);
    if (tid < D_S)
        qs[tid] = q[(long)(b*SL + l)*(NH*D_S) + h*D_S + tid];
    for (int j = tid; j < SL; j += 256) eff_s[j] = 0.f;
    __syncthreads();
    for (int j = wid; j <= l; j += 4) {
        const float* mup = mu + (long)(b*SL + j)*D_S;
        const float* ivp = iv + (long)(b*SL + j)*D_S;
        float t0 = qs[lane]      - mup[lane];
        float t1 = qs[lane + 64] - mup[lane + 64];
        float s = ivp[lane]*t0*t0 + ivp[lane + 64]*t1*t1;
        #pragma unroll
        for (int o = 32; o > 0; o >>= 1) s += __shfl_xor(s, o);
        if (lane == 0) {
            float Kv = expf(scale * s);
            float e  = fminf(alpha[b*SL + j] * Kv, 1.f - 1e-6f);
            eff_s[j] = e;
        }
    }
    __syncthreads();
    if (wid == 0) {
        float carry = 0.f;
        long orow = (((long)b*NH + h)*SL + l)*SL;
        for (int c = 0; c < SL/64; c++) {
            int j = c*64 + lane;
            float e  = eff_s[j];
            float le = log1pf(-e);
            float sc = le;
            #pragma unroll
            for (int o = 1; o < 64; o <<= 1) {
                float v = __shfl_up(sc, o);
                if (lane >= o) sc += v;
            }
            float logT = carry + sc - le;
            wout[orow + j] = e * expf(logT);
            carry += __shfl(sc, 63);
        }
    }
}

__global__ __launch_bounds__(256) void build_x(
    const float* __restrict__ feats, const float* __restrict__ meaning,
    float* __restrict__ x)
{
    long i = (long)blockIdx.x*256 + threadIdx.x;
    if (i < (long)BL*D_F) {
        int r = (int)(i / D_F), c = (int)(i % D_F);
        x[(long)r*2*D_F + c]       = feats[i];
        x[(long)r*2*D_F + D_F + c] = meaning[i];
    }
}

__global__ __launch_bounds__(256) void gate_kernel(
    const float* __restrict__ x, const float* __restrict__ Wg,
    const float* __restrict__ bg, float* __restrict__ alpha)
{
    int r = blockIdx.x;
    int tid = threadIdx.x, lane = tid & 63, wid = tid >> 6;
    float s = 0.f;
    for (int c = tid; c < 2*D_F; c += 256)
        s += x[(long)r*2*D_F + c] * Wg[c];
    #pragma unroll
    for (int o = 32; o > 0; o >>= 1) s += __shfl_xor(s, o);
    __shared__ float red[4];
    if (lane == 0) red[wid] = s;
    __syncthreads();
    if (tid == 0) {
        float t = red[0] + red[1] + red[2] + red[3] + bg[0];
        alpha[r] *= 1.f / (1.f + expf(-t));
    }
}

__global__ __launch_bounds__(256) void ln_kernel(
    const float* __restrict__ x, const float* __restrict__ g,
    const float* __restrict__ bsh, float* __restrict__ o, int D)
{
    int r = blockIdx.x;
    const float* xr = x + (long)r*D;
    int tid = threadIdx.x, lane = tid & 63, wid = tid >> 6;
    float s = 0.f, s2 = 0.f;
    for (int c = tid; c < D; c += 256) { float v = xr[c]; s += v; s2 += v*v; }
    #pragma unroll
    for (int o = 32; o > 0; o >>= 1) { s += __shfl_xor(s, o); s2 += __shfl_xor(s2, o); }
    __shared__ float rs[4], rs2[4], stat[2];
    if (lane == 0) { rs[wid] = s; rs2[wid] = s2; }
    __syncthreads();
    if (tid == 0) {
        float a = rs[0] + rs[1] + rs[2] + rs[3];
        float bb = rs2[0] + rs2[1] + rs2[2] + rs2[3];
        float mean = a / D;
        float var = bb / D - mean*mean;
        if (var < 0.f) var = 0.f;
        stat[0] = mean;
        stat[1] = 1.f / sqrtf(var + 1e-5f);
    }
    __syncthreads();
    float mean = stat[0], inv = stat[1];
    for (int c = tid; c < D; c += 256)
        o[(long)r*D + c] = (xr[c] - mean)*inv*g[c] + bsh[c];
}

// ============================ launch ============================
extern "C" void kernel_launch(void* const* d_in, const int* in_sizes, int n_in,
                              void* d_out, int out_size, void* d_ws, size_t ws_size,
                              hipStream_t stream)
{
    const int*   tokens  = (const int*)  d_in[0];
    const float* tok_mu  = (const float*)d_in[1];
    const float* tok_lv  = (const float*)d_in[2];
    const float* tok_ra  = (const float*)d_in[3];
    const float* tok_f   = (const float*)d_in[4];
    const float* pos_mu  = (const float*)d_in[5];
    const float* log_tau = (const float*)d_in[6];
    const float* Wq      = (const float*)d_in[7];
    const float* bq      = (const float*)d_in[8];
    const float* Whead   = (const float*)d_in[9];
    const float* bhead   = (const float*)d_in[10];
    const float* Wmu     = (const float*)d_in[11];
    const float* bmu     = (const float*)d_in[12];
    const float* Wg      = (const float*)d_in[13];
    const float* bg      = (const float*)d_in[14];
    const float* ln_g    = (const float*)d_in[15];
    const float* ln_b    = (const float*)d_in[16];
    const float* W1      = (const float*)d_in[17];
    const float* b1      = (const float*)d_in[18];
    const float* W2      = (const float*)d_in[19];
    const float* b2      = (const float*)d_in[20];
    const float* lnf_g   = (const float*)d_in[21];
    const float* lnf_b   = (const float*)d_in[22];
    const float* Wlm     = (const float*)d_in[23];
    float* out = (float*)d_out;

    // ---- workspace carve (fp32 region kept for fallback compatibility) ----
    float* ws = (float*)d_ws;
    size_t off = 0;
    auto alloc = [&](size_t n) { float* p = ws + off; off += n; return p; };
    float* mu      = alloc((size_t)BL*D_S);
    float* iv      = alloc((size_t)BL*D_S);
    float* alpha   = alloc((size_t)BL);
    float* feats   = alloc((size_t)BL*D_F);
    float* q       = alloc((size_t)BL*NH*D_S);     // fallback only
    float* w       = alloc((size_t)NB*NH*SL*SL);   // mahal S buffer (mfma) / w (fallback)
    float* mh      = alloc((size_t)BL*NH*D_F);     // fallback only
    float* meaning = alloc((size_t)BL*D_F);
    float* x       = alloc((size_t)BL*2*D_F);      // fallback only
    float* hbuf = w;
    float* y    = w;
    float* t    = mh;

    size_t offb = (off*sizeof(float) + 255) & ~(size_t)255;
    auto alloc16 = [&](size_t n) {
        u16* p = (u16*)((char*)d_ws + offb);
        offb = (offb + n*2 + 255) & ~(size_t)255;
        return p;
    };
    u16 *AbigH  = alloc16((size_t)2048*4000), *AbigL  = alloc16((size_t)2048*4000);
    u16 *AmuH   = alloc16((size_t)2048*128),  *AmuL   = alloc16((size_t)2048*128);
    u16 *WqH    = alloc16((size_t)512*128),   *WqL    = alloc16((size_t)512*128);
    u16 *WheadH = alloc16((size_t)1024*4000), *WheadL = alloc16((size_t)1024*4000);
    u16 *WmuH   = alloc16((size_t)256*2016),  *WmuL   = alloc16((size_t)256*2016);
    u16 *W1H    = alloc16((size_t)2*4096*2016), *W1L  = alloc16((size_t)2*4096*2016);
    u16 *W2H    = alloc16((size_t)2*1024*4000), *W2L  = alloc16((size_t)2*1024*4000);
    u16 *WlmH   = alloc16((size_t)32000*1024),  *WlmL = alloc16((size_t)32000*1024);
    u16 *AeH    = alloc16((size_t)8192*288),  *AeL    = alloc16((size_t)8192*288);
    u16 *BeH    = alloc16((size_t)2048*288),  *BeL    = alloc16((size_t)2048*288);
    u16 *wH     = alloc16((size_t)8192*512),  *wL     = alloc16((size_t)8192*512);
    u16 *fTH    = alloc16((size_t)4*1024*512),*fTL    = alloc16((size_t)4*1024*512);
    const bool use_mfma = ws_size >= offb;

    // aliases (lifetime-disjoint reuse, see sequencing comments below)
    u16 *XH = AbigH, *XL = AbigL;       // x-split [2048][2016]  (after mh-split dead)
    u16 *HHp = wH,  *HLp = wL;          // h-split [2048][2016]  (after w-split dead)
    u16 *yH = AbigH, *yL = AbigL;       // y-split [2048][1024]  (after last mh dead)

    auto SPL = [&](const float* W_, u16* H_, u16* L_, int N_, int K_, int Np_, int Kp_) {
        long t4 = (long)Np_ * Kp_ / 4;
        int nb = (int)((t4 + 255) / 256);
        if (nb > 2048) nb = 2048;
        split_hl<<<nb, 256, 0, stream>>>(W_, H_, L_, N_, K_, Np_, Kp_);
    };

    gather_kernel<<<BL, 256, 0, stream>>>(tokens, tok_mu, tok_lv, tok_ra, tok_f,
                                          pos_mu, mu, iv, alpha, feats);

    if (use_mfma) {
        aext_tail<<<1024, 256, 0, stream>>>(AeH, AeL);
        // one-time weight splits
        SPL(Wq,    WqH,    WqL,    512,   128,  512,   128);
        SPL(Whead, WheadH, WheadL, 1000,  4000, 1024,  4000);
        SPL(Wmu,   WmuH,   WmuL,   256,   2000, 256,   2016);
        for (int p = 0; p < 2; p++) {
            SPL(W1 + (size_t)p*4000*2000, W1H + (size_t)p*4096*2016,
                W1L + (size_t)p*4096*2016, 4000, 2000, 4096, 2016);
            SPL(W2 + (size_t)p*1000*4000, W2H + (size_t)p*1024*4000,
                W2L + (size_t)p*1024*4000, 1000, 4000, 1024, 4000);
        }
        SPL(Wlm, WlmH, WlmL, 32000, 1000, 32000, 1024);

        for (int p = 0; p < NP; p++) {
            // q = mu @ Wq.T + bq, epilogue writes Aext [q^2, q] directly
            SPL(mu, AmuH, AmuL, 2048, 128, 2048, 128);
            gemm_bf3<6><<<dim3(4, 16), 256, 0, stream>>>(
                AmuH, AmuL, WqH, WqL, bq, nullptr, AeH, AeL, BL, NH*D_S, 128);
            build_b_ext<<<2048, 256, 0, stream>>>(mu, iv, BeH, BeL);
            gemm_mahal<<<dim3(4, 4, 16), 256, 0, stream>>>(AeH, AeL, BeH, BeL, w);
            scan_kernel<<<2048, 256, 0, stream>>>(w, alpha, log_tau, wH, wL);
            tsplit_feats<<<dim3(32, 16, NB), 256, 0, stream>>>(feats, fTH, fTL);
            // mh split-stored into Abig [2048][4000]
            gemm_mh_bf3<<<dim3(8, 16, NB), 256, 0, stream>>>(wH, wL, fTH, fTL, AbigH, AbigL);
            // meaning = mh @ Whead.T + bhead
            gemm_bf3<1><<<dim3(8, 16), 256, 0, stream>>>(
                AbigH, AbigL, WheadH, WheadL, bhead, meaning, nullptr, nullptr,
                BL, D_F, 4000);
            if (p < NP - 1) {
                // fused concat+gate+LN; writes x-split (Abig region, mh dead)
                // and h-split (w-split region, w dead after gemm_mh)
                fuse_xgl<<<BL, 256, 0, stream>>>(
                    feats, meaning, Wg + (size_t)p*2*D_F, bg + p, alpha,
                    ln_g + (size_t)p*2*D_F, ln_b + (size_t)p*2*D_F,
                    XH, XL, HHp, HLp);
                // mu += tanh(x @ Wmu[p].T + bmu[p])
                gemm_bf3<4><<<dim3(1, 16), 256, 0, stream>>>(
                    XH, XL, WmuH + (size_t)p*128*2016, WmuL + (size_t)p*128*2016,
                    bmu + (size_t)p*D_S, mu, nullptr, nullptr, BL, D_S, 2016);
                // t = gelu(h @ W1.T + b1), split-stored into Abig (x dead after Wmu)
                gemm_bf3<5><<<dim3(32, 16), 256, 0, stream>>>(
                    HHp, HLp, W1H + (size_t)p*4096*2016, W1L + (size_t)p*4096*2016,
                    b1 + (size_t)p*4*D_F, nullptr, AbigH, AbigL, BL, 4*D_F, 2016);
                // feats += t @ W2.T + b2
                gemm_bf3<3><<<dim3(8, 16), 256, 0, stream>>>(
                    AbigH, AbigL, W2H + (size_t)p*1024*4000, W2L + (size_t)p*1024*4000,
                    b2 + (size_t)p*D_F, feats, nullptr, nullptr, BL, D_F, 4000);
            }
        }
        // y = LN(meaning) split-stored; out = y @ Wlm.T
        ln_split<<<BL, 256, 0, stream>>>(meaning, lnf_g, lnf_b, yH, yL, D_F, 1024);
        gemm_bf3<0><<<dim3(250, 16), 256, 0, stream>>>(
            yH, yL, WlmH, WlmL, nullptr, out, nullptr, nullptr, BL, 32000, 1024);
    } else {
        // ---- fp32 fallback ----
        for (int p = 0; p < NP; p++) {
            gemm_tn<1><<<dim3(8, 32), 256, 0, stream>>>(mu, Wq, bq, q, BL, NH*D_S, D_S);
            attn_kernel<<<dim3(SL, NH, NB), 256, 0, stream>>>(q, mu, iv, alpha, log_tau, w);
            gemm_mh<<<dim3(16, 32, NB), 256, 0, stream>>>(w, feats, mh);
            gemm_tn<1><<<dim3(16, 32), 256, 0, stream>>>(mh, Whead, bhead, meaning, BL, D_F, NH*D_F);
            if (p < NP - 1) {
                build_x<<<(BL*D_F + 255)/256, 256, 0, stream>>>(feats, meaning, x);
                gate_kernel<<<BL, 256, 0, stream>>>(x, Wg + (size_t)p*2*D_F, bg + p, alpha);
                gemm_tn<4><<<dim3(2, 32), 256, 0, stream>>>(x, Wmu + (size_t)p*D_S*2*D_F,
                                                            bmu + (size_t)p*D_S, mu, BL, D_S, 2*D_F);
                ln_kernel<<<BL, 256, 0, stream>>>(x, ln_g + (size_t)p*2*D_F, ln_b + (size_t)p*2*D_F,
                                                  hbuf, 2*D_F);
                gemm_tn<2><<<dim3(63, 32), 256, 0, stream>>>(hbuf, W1 + (size_t)p*4*D_F*2*D_F,
                                                             b1 + (size_t)p*4*D_F, t, BL, 4*D_F, 2*D_F);
                gemm_tn<3><<<dim3(16, 32), 256, 0, stream>>>(t, W2 + (size_t)p*D_F*4*D_F,
                                                             b2 + (size_t)p*D_F, feats, BL, D_F, 4*D_F);
            }
        }
        ln_kernel<<<BL, 256, 0, stream>>>(meaning, lnf_g, lnf_b, y, D_F);
        gemm_tn<0><<<dim3(500, 32), 256, 0, stream>>>(y, Wlm, nullptr, out, BL, 32000, D_F);
    }
}